// Round 1
// baseline (3231.401 us; speedup 1.0000x reference)
//
#include <hip/hip_runtime.h>
#include <math.h>

#define Bb   32
#define SQ   257
#define Dm   1024
#define HD   64
#define Ee   8
#define Rr   16
#define GHh  256
#define NT   (Bb*SQ)   // 8224

// ---------------------------------------------------------------- gating ----
__global__ __launch_bounds__(256) void gating_kernel(
    const float* __restrict__ x, const float* __restrict__ gw1,
    const float* __restrict__ gb1, const float* __restrict__ gw2,
    const float* __restrict__ gb2,
    float* __restrict__ gates, int* __restrict__ idx)
{
    __shared__ float pooled[Dm];
    __shared__ float hbuf[GHh];
    __shared__ float logits[Ee];
    const int b = blockIdx.x;
    const int t = threadIdx.x;

    for (int d = t; d < Dm; d += 256) {
        float s = 0.f;
        const float* xp = x + (size_t)b * SQ * Dm + d;
        for (int si = 0; si < SQ; ++si) s += xp[(size_t)si * Dm];
        pooled[d] = s * (1.0f / SQ);
    }
    __syncthreads();
    {
        const float* w = gw1 + (size_t)t * Dm;
        float s = 0.f;
        for (int d = 0; d < Dm; ++d) s += pooled[d] * w[d];
        s += gb1[t];
        hbuf[t] = s > 0.f ? s : 0.f;
    }
    __syncthreads();
    if (t < Ee) {
        const float* w = gw2 + t * GHh;
        float s = 0.f;
        for (int j = 0; j < GHh; ++j) s += hbuf[j] * w[j];
        logits[t] = s + gb2[t];
    }
    __syncthreads();
    if (t == 0) {
        int i1 = 0; float v1 = logits[0];
        for (int e = 1; e < Ee; ++e) if (logits[e] > v1) { v1 = logits[e]; i1 = e; }
        int i2 = 0; float v2 = -1e30f;
        for (int e = 0; e < Ee; ++e) if (e != i1 && logits[e] > v2) { v2 = logits[e]; i2 = e; }
        float e1 = __expf(v1 - v1), e2 = __expf(v2 - v1);
        float inv = 1.f / (e1 + e2);
        gates[b*2+0] = e1 * inv; gates[b*2+1] = e2 * inv;
        idx[b*2+0] = i1; idx[b*2+1] = i2;
    }
}

// ------------------------------------------- expert subspace projections ----
// out[m][k*16+r] = gates[b][k] * S[e_k][r] * dot(x[m,:], V[e_k][r][:])
__global__ __launch_bounds__(256) void xvs_kernel(
    const float* __restrict__ x,
    const float* __restrict__ V0, const float* __restrict__ S0, float* __restrict__ o0,
    const float* __restrict__ V1, const float* __restrict__ S1, float* __restrict__ o1,
    const float* __restrict__ V2, const float* __restrict__ S2, float* __restrict__ o2,
    const float* __restrict__ gates, const int* __restrict__ idx, int nproj)
{
    __shared__ float xrow[Dm];
    const int m = blockIdx.x;
    const int b = m / SQ;
    const int t = threadIdx.x;
    const int lane = t & 63;
    const int wave = t >> 6;

    for (int d = t; d < Dm; d += 256) xrow[d] = x[(size_t)m * Dm + d];
    __syncthreads();

    const int e0 = idx[b*2+0], e1i = idx[b*2+1];
    const float g0 = gates[b*2+0], g1 = gates[b*2+1];

    for (int p = 0; p < nproj; ++p) {
        const float* V  = (p == 0) ? V0 : (p == 1) ? V1 : V2;
        const float* Sp = (p == 0) ? S0 : (p == 1) ? S1 : S2;
        float* out      = (p == 0) ? o0 : (p == 1) ? o1 : o2;
        for (int j = wave; j < 32; j += 4) {
            const int k = j >> 4, r = j & 15;
            const int e = (k == 0) ? e0 : e1i;
            const float g = (k == 0) ? g0 : g1;
            const float* vrow = V + ((size_t)e * Rr + r) * Dm;
            float s = 0.f;
            for (int d = lane; d < Dm; d += 64) s += xrow[d] * vrow[d];
            for (int off = 32; off > 0; off >>= 1) s += __shfl_down(s, off, 64);
            if (lane == 0) out[(size_t)m * 32 + j] = s * g * Sp[e * Rr + r];
        }
    }
}

// ------------------------------------------------ main GEMM + fused MoE -----
// y[b,s,n] = scale * ( sum_d x[b,s,d]*W[n,d] + bias[n]
//                      + sum_j xvs[b,s,j]*U[e(j)][n][r(j)] )
__global__ __launch_bounds__(256) void gemm_kernel(
    const float* __restrict__ x, const float* __restrict__ W,
    const float* __restrict__ U, const float* __restrict__ bias,
    const float* __restrict__ xvs, const int* __restrict__ idx,
    float scale, float* __restrict__ y)
{
    __shared__ float as[16][64];
    __shared__ float bs[16][64];
    __shared__ float xvsh[64][32];
    const int nb = blockIdx.x;   // 16 tiles of N
    const int sb = blockIdx.y;   // 5 tiles of S
    const int b  = blockIdx.z;
    const int t  = threadIdx.x;
    const int tx = t & 15, ty = t >> 4;
    const int n0 = nb * 64, s0 = sb * 64;

    // stage xvs tile
    for (int i = t; i < 64 * 32; i += 256) {
        int row = i >> 5, col = i & 31;
        int s = s0 + row;
        xvsh[row][col] = (s < SQ) ? xvs[((size_t)(b * SQ + s)) * 32 + col] : 0.f;
    }

    float acc[4][4] = {};
    const int lr = t >> 2;
    const int lk = (t & 3) * 4;

    for (int k0 = 0; k0 < Dm; k0 += 16) {
        const int s = s0 + lr;
        float4 xa = make_float4(0.f, 0.f, 0.f, 0.f);
        if (s < SQ) xa = *(const float4*)(x + ((size_t)(b * SQ + s)) * Dm + k0 + lk);
        float4 wa = *(const float4*)(W + ((size_t)(n0 + lr)) * Dm + k0 + lk);
        __syncthreads();
        as[lk+0][lr] = xa.x; as[lk+1][lr] = xa.y; as[lk+2][lr] = xa.z; as[lk+3][lr] = xa.w;
        bs[lk+0][lr] = wa.x; bs[lk+1][lr] = wa.y; bs[lk+2][lr] = wa.z; bs[lk+3][lr] = wa.w;
        __syncthreads();
        #pragma unroll
        for (int kk = 0; kk < 16; ++kk) {
            float4 a4 = *(const float4*)&as[kk][ty * 4];
            float4 b4 = *(const float4*)&bs[kk][tx * 4];
            float av[4] = {a4.x, a4.y, a4.z, a4.w};
            float bv[4] = {b4.x, b4.y, b4.z, b4.w};
            #pragma unroll
            for (int i = 0; i < 4; ++i)
                #pragma unroll
                for (int j = 0; j < 4; ++j)
                    acc[i][j] += av[i] * bv[j];
        }
    }

    const int e0 = idx[b*2+0], e1i = idx[b*2+1];
    #pragma unroll
    for (int i = 0; i < 4; ++i) {
        const int s = s0 + ty * 4 + i;
        if (s >= SQ) continue;
        #pragma unroll
        for (int j = 0; j < 4; ++j) {
            const int n = n0 + tx * 4 + j;
            const float* u0 = U + ((size_t)e0 * Dm + n) * Rr;
            const float* u1 = U + ((size_t)e1i * Dm + n) * Rr;
            float v = acc[i][j] + bias[n];
            float lsum = 0.f;
            #pragma unroll
            for (int r = 0; r < Rr; ++r) lsum += xvsh[ty*4+i][r] * u0[r];
            #pragma unroll
            for (int r = 0; r < Rr; ++r) lsum += xvsh[ty*4+i][16+r] * u1[r];
            y[((size_t)(b * SQ + s)) * Dm + n] = (v + lsum) * scale;
        }
    }
}

// -------------------------------------------------------------- attention ---
__global__ __launch_bounds__(256) void attn_kernel(
    const float* __restrict__ q, const float* __restrict__ k,
    const float* __restrict__ v, float* __restrict__ ctx)
{
    __shared__ float qs[32][68];
    __shared__ float kv[64][68];
    __shared__ float sc[32][264];
    const int qt = blockIdx.x;   // 9 tiles of 32 q-rows
    const int h  = blockIdx.y;
    const int b  = blockIdx.z;
    const int t  = threadIdx.x;
    const size_t base = (size_t)b * SQ * Dm + (size_t)h * HD;

    {
        const int d = t & 63;
        for (int r = t >> 6; r < 32; r += 4) {
            const int s = qt * 32 + r;
            qs[r][d] = (s < SQ) ? q[base + (size_t)s * Dm + d] : 0.f;
        }
    }
    const int qi = t >> 3, l8 = t & 7;
    for (int kt = 0; kt < 5; ++kt) {
        __syncthreads();
        {
            const int d = t & 63;
            for (int r = t >> 6; r < 64; r += 4) {
                const int s = kt * 64 + r;
                kv[r][d] = (s < SQ) ? k[base + (size_t)s * Dm + d] : 0.f;
            }
        }
        __syncthreads();
        for (int jj = l8; jj < 64; jj += 8) {
            const int j = kt * 64 + jj;
            if (j >= SQ) break;
            float s = 0.f;
            #pragma unroll
            for (int d = 0; d < 64; d += 4) {
                float4 a = *(const float4*)&qs[qi][d];
                float4 c = *(const float4*)&kv[jj][d];
                s += a.x * c.x + a.y * c.y + a.z * c.z + a.w * c.w;
            }
            sc[qi][j] = s;
        }
    }
    __syncthreads();
    {
        float m = -1e30f;
        for (int j = l8; j < SQ; j += 8) m = fmaxf(m, sc[qi][j]);
        for (int off = 1; off < 8; off <<= 1) m = fmaxf(m, __shfl_xor(m, off, 64));
        float l = 0.f;
        for (int j = l8; j < SQ; j += 8) { float e = __expf(sc[qi][j] - m); sc[qi][j] = e; l += e; }
        for (int off = 1; off < 8; off <<= 1) l += __shfl_xor(l, off, 64);
        const float inv = 1.f / l;
        for (int j = l8; j < SQ; j += 8) sc[qi][j] *= inv;
    }
    float acc[8] = {};
    const int d = t & 63, qg = (t >> 6) * 8;
    for (int vt = 0; vt < 5; ++vt) {
        __syncthreads();
        for (int r = t >> 6; r < 64; r += 4) {
            const int s = vt * 64 + r;
            kv[r][d] = (s < SQ) ? v[base + (size_t)s * Dm + d] : 0.f;
        }
        __syncthreads();
        const int jmax = (SQ - vt * 64) < 64 ? (SQ - vt * 64) : 64;
        for (int jj = 0; jj < jmax; ++jj) {
            const float vv = kv[jj][d];
            const int j = vt * 64 + jj;
            #pragma unroll
            for (int r = 0; r < 8; ++r) acc[r] += sc[qg + r][j] * vv;
        }
    }
    #pragma unroll
    for (int r = 0; r < 8; ++r) {
        const int s = qt * 32 + qg + r;
        if (s < SQ) ctx[base + (size_t)s * Dm + d] = acc[r];
    }
}

// ------------------------------------------------------------------ launch --
extern "C" void kernel_launch(void* const* d_in, const int* in_sizes, int n_in,
                              void* d_out, int out_size, void* d_ws, size_t ws_size,
                              hipStream_t stream)
{
    const float* x   = (const float*)d_in[0];
    const float* gw1 = (const float*)d_in[1];
    const float* gb1 = (const float*)d_in[2];
    const float* gw2 = (const float*)d_in[3];
    const float* gb2 = (const float*)d_in[4];
    const float *Wm[4], *U[4], *Sv[4], *Vv[4], *bias[4];
    for (int p = 0; p < 4; ++p) {
        Wm[p]   = (const float*)d_in[5 + p*5 + 0];
        U[p]    = (const float*)d_in[5 + p*5 + 1];
        Sv[p]   = (const float*)d_in[5 + p*5 + 2];
        Vv[p]   = (const float*)d_in[5 + p*5 + 3];
        bias[p] = (const float*)d_in[5 + p*5 + 4];
    }
    float* ws    = (float*)d_ws;
    float* gates = ws;                      // 64 floats
    int*   idx   = (int*)(ws + 64);         // 64 ints
    float* xvs_q = ws + 128;
    float* xvs_k = xvs_q + (size_t)NT * 32;
    float* xvs_v = xvs_k + (size_t)NT * 32;
    float* xvs_o = xvs_v + (size_t)NT * 32;
    float* qb    = xvs_o + (size_t)NT * 32;
    float* kb    = qb + (size_t)NT * Dm;
    float* vb    = kb + (size_t)NT * Dm;
    float* cb    = vb + (size_t)NT * Dm;

    gating_kernel<<<Bb, 256, 0, stream>>>(x, gw1, gb1, gw2, gb2, gates, idx);
    xvs_kernel<<<NT, 256, 0, stream>>>(x, Vv[0], Sv[0], xvs_q,
                                          Vv[1], Sv[1], xvs_k,
                                          Vv[2], Sv[2], xvs_v, gates, idx, 3);
    dim3 g(16, 5, Bb);
    gemm_kernel<<<g, 256, 0, stream>>>(x, Wm[0], U[0], bias[0], xvs_q, idx, 0.125f, qb);
    gemm_kernel<<<g, 256, 0, stream>>>(x, Wm[1], U[1], bias[1], xvs_k, idx, 1.0f,  kb);
    gemm_kernel<<<g, 256, 0, stream>>>(x, Wm[2], U[2], bias[2], xvs_v, idx, 1.0f,  vb);
    attn_kernel<<<dim3(9, 16, Bb), 256, 0, stream>>>(qb, kb, vb, cb);
    xvs_kernel<<<NT, 256, 0, stream>>>(cb, Vv[3], Sv[3], xvs_o,
                                          nullptr, nullptr, nullptr,
                                          nullptr, nullptr, nullptr, gates, idx, 1);
    gemm_kernel<<<g, 256, 0, stream>>>(cb, Wm[3], U[3], bias[3], xvs_o, idx, 1.0f, (float*)d_out);
}

// Round 2
// 1811.056 us; speedup vs baseline: 1.7843x; 1.7843x over previous
//
#include <hip/hip_runtime.h>
#include <math.h>

#define Bb   32
#define SQ   257
#define Dm   1024
#define HD   64
#define Ee   8
#define Rr   16
#define GHh  256
#define NT   (Bb*SQ)   // 8224
#define KX   1152      // 1024 + E*R extension

typedef unsigned short ush;
typedef __attribute__((ext_vector_type(8))) short short8;
typedef __attribute__((ext_vector_type(4))) float floatx4;
typedef __attribute__((ext_vector_type(4))) unsigned short ushort4v;

__device__ __forceinline__ ush f2bf(float f) {
    union { float f; unsigned u; } a; a.f = f;
    unsigned r = a.u + 0x7fff + ((a.u >> 16) & 1);   // RNE
    return (ush)(r >> 16);
}
__device__ __forceinline__ float bf2f(ush u) {
    union { unsigned u; float f; } a; a.u = ((unsigned)u) << 16; return a.f;
}
__device__ __forceinline__ void load16(const ush* g, ush* l) {
    __builtin_amdgcn_global_load_lds(
        (const __attribute__((address_space(1))) unsigned int*)g,
        (__attribute__((address_space(3))) unsigned int*)l,
        16, 0, 0);
}

// ---------------------------------------------------------------- gating ----
__global__ __launch_bounds__(256) void gating_kernel(
    const float* __restrict__ x, const float* __restrict__ gw1,
    const float* __restrict__ gb1, const float* __restrict__ gw2,
    const float* __restrict__ gb2,
    float* __restrict__ gates, int* __restrict__ idx)
{
    __shared__ float pooled[Dm];
    __shared__ float hbuf[GHh];
    __shared__ float logits[Ee];
    const int b = blockIdx.x;
    const int t = threadIdx.x;

    for (int d = t; d < Dm; d += 256) {
        float s = 0.f;
        const float* xp = x + (size_t)b * SQ * Dm + d;
        for (int si = 0; si < SQ; ++si) s += xp[(size_t)si * Dm];
        pooled[d] = s * (1.0f / SQ);
    }
    __syncthreads();
    {
        const float* w = gw1 + (size_t)t * Dm;
        float s = 0.f;
        for (int d = 0; d < Dm; ++d) s += pooled[d] * w[d];
        s += gb1[t];
        hbuf[t] = s > 0.f ? s : 0.f;
    }
    __syncthreads();
    if (t < Ee) {
        const float* w = gw2 + t * GHh;
        float s = 0.f;
        for (int j = 0; j < GHh; ++j) s += hbuf[j] * w[j];
        logits[t] = s + gb2[t];
    }
    __syncthreads();
    if (t == 0) {
        int i1 = 0; float v1 = logits[0];
        for (int e = 1; e < Ee; ++e) if (logits[e] > v1) { v1 = logits[e]; i1 = e; }
        int i2 = 0; float v2 = -1e30f;
        for (int e = 0; e < Ee; ++e) if (e != i1 && logits[e] > v2) { v2 = logits[e]; i2 = e; }
        float e1 = __expf(v1 - v1), e2 = __expf(v2 - v1);
        float inv = 1.f / (e1 + e2);
        gates[b*2+0] = e1 * inv; gates[b*2+1] = e2 * inv;
        idx[b*2+0] = i1; idx[b*2+1] = i2;
    }
}

// ------------------------------------------------ fp32 -> split bf16 (rows) -
__global__ __launch_bounds__(256) void convx_kernel(
    const float* __restrict__ x, ush* __restrict__ xh, ush* __restrict__ xl)
{
    const int m = blockIdx.x, t = threadIdx.x;
    float4 v = *(const float4*)(x + (size_t)m * Dm + t * 4);
    ushort4v hv, lv;
    hv.x = f2bf(v.x); lv.x = f2bf(v.x - bf2f(hv.x));
    hv.y = f2bf(v.y); lv.y = f2bf(v.y - bf2f(hv.y));
    hv.z = f2bf(v.z); lv.z = f2bf(v.z - bf2f(hv.z));
    hv.w = f2bf(v.w); lv.w = f2bf(v.w - bf2f(hv.w));
    *(ushort4v*)(xh + (size_t)m * Dm + t * 4) = hv;
    *(ushort4v*)(xl + (size_t)m * Dm + t * 4) = lv;
}

// --------------------------------- W,U -> split bf16 B matrix (1024 x 1152) -
__global__ __launch_bounds__(256) void convB_kernel(
    const float* __restrict__ W, const float* __restrict__ U,
    ush* __restrict__ Bh, ush* __restrict__ Bl)
{
    const int i = blockIdx.x * 256 + threadIdx.x;   // 1024*288 total
    const int n = i / 288, c4 = i % 288, col = c4 * 4;
    float4 v;
    if (col < Dm) {
        v = *(const float4*)(W + (size_t)n * Dm + col);
    } else {
        int ec = col - Dm, e = ec >> 4, r = ec & 15;
        v = *(const float4*)(U + ((size_t)(e * Dm + n)) * Rr + r);
    }
    ushort4v hv, lv;
    hv.x = f2bf(v.x); lv.x = f2bf(v.x - bf2f(hv.x));
    hv.y = f2bf(v.y); lv.y = f2bf(v.y - bf2f(hv.y));
    hv.z = f2bf(v.z); lv.z = f2bf(v.z - bf2f(hv.z));
    hv.w = f2bf(v.w); lv.w = f2bf(v.w - bf2f(hv.w));
    *(ushort4v*)(Bh + (size_t)n * KX + col) = hv;
    *(ushort4v*)(Bl + (size_t)n * KX + col) = lv;
}

// -------------------- expert-subspace ext columns: g*S*(x.V) as split bf16 --
__global__ __launch_bounds__(256) void ext_kernel(
    const float* __restrict__ x,
    const float* __restrict__ V0, const float* __restrict__ S0, ush* __restrict__ h0, ush* __restrict__ l0,
    const float* __restrict__ V1, const float* __restrict__ S1, ush* __restrict__ h1, ush* __restrict__ l1,
    const float* __restrict__ V2, const float* __restrict__ S2, ush* __restrict__ h2, ush* __restrict__ l2,
    const float* __restrict__ gates, const int* __restrict__ idx, int nproj)
{
    __shared__ float xrow[Dm];
    const int m = blockIdx.x, b = m / SQ, t = threadIdx.x;
    const int lane = t & 63, wave = t >> 6;

    for (int d = t; d < Dm; d += 256) xrow[d] = x[(size_t)m * Dm + d];
    for (int p = 0; p < nproj; ++p) {
        ush* hh = p == 0 ? h0 : p == 1 ? h1 : h2;
        ush* ll = p == 0 ? l0 : p == 1 ? l1 : l2;
        for (int c = t; c < 128; c += 256) {
            hh[(size_t)m * 128 + c] = 0; ll[(size_t)m * 128 + c] = 0;
        }
    }
    __syncthreads();
    const int e0 = idx[b*2+0], e1 = idx[b*2+1];
    const float g0 = gates[b*2+0], g1 = gates[b*2+1];
    const int ndot = nproj * 32;
    for (int j = wave; j < ndot; j += 4) {
        const int p = j >> 5, jj = j & 31, kk = jj >> 4, r = jj & 15;
        const float* V  = p == 0 ? V0 : p == 1 ? V1 : V2;
        const float* Sp = p == 0 ? S0 : p == 1 ? S1 : S2;
        ush* hh = p == 0 ? h0 : p == 1 ? h1 : h2;
        ush* ll = p == 0 ? l0 : p == 1 ? l1 : l2;
        const int e = kk ? e1 : e0;
        const float g = kk ? g1 : g0;
        const float* vr = V + ((size_t)e * Rr + r) * Dm;
        float s = 0.f;
        for (int d = lane; d < Dm; d += 64) s += xrow[d] * vr[d];
        for (int off = 32; off > 0; off >>= 1) s += __shfl_down(s, off, 64);
        if (lane == 0) {
            float val = s * g * Sp[e * Rr + r];
            ush hv = f2bf(val);
            hh[(size_t)m * 128 + e * 16 + r] = hv;
            ll[(size_t)m * 128 + e * 16 + r] = f2bf(val - bf2f(hv));
        }
    }
}

// -------------------------------- split-bf16 MFMA GEMM, K=1152 (1024+ext) ---
__global__ __launch_bounds__(256) void gemm_mfma(
    const ush* __restrict__ xh, const ush* __restrict__ xl,
    const ush* __restrict__ e0h, const ush* __restrict__ e0l,
    const ush* __restrict__ e1h, const ush* __restrict__ e1l,
    const ush* __restrict__ e2h, const ush* __restrict__ e2l,
    const ush* __restrict__ B0h, const ush* __restrict__ B0l,
    const ush* __restrict__ B1h, const ush* __restrict__ B1l,
    const ush* __restrict__ B2h, const ush* __restrict__ B2l,
    const float* __restrict__ b0, const float* __restrict__ b1, const float* __restrict__ b2,
    float* __restrict__ y0, float* __restrict__ y1, float* __restrict__ y2,
    float scale0)
{
    const int z = blockIdx.z;
    const ush* Eh = z == 0 ? e0h : z == 1 ? e1h : e2h;
    const ush* El = z == 0 ? e0l : z == 1 ? e1l : e2l;
    const ush* Bh = z == 0 ? B0h : z == 1 ? B1h : B2h;
    const ush* Bl = z == 0 ? B0l : z == 1 ? B1l : B2l;
    const float* bias = z == 0 ? b0 : z == 1 ? b1 : b2;
    float* y = z == 0 ? y0 : z == 1 ? y1 : y2;
    const float scale = z == 0 ? scale0 : 1.0f;

    __shared__ ush sAh[128*32], sAl[128*32], sBh[128*32], sBl[128*32];
    const int t = threadIdx.x, lane = t & 63, w = t >> 6;
    const int m0 = blockIdx.y * 128, n0 = blockIdx.x * 128;

    floatx4 acc[4][4] = {};

    const int srow = w * 32 + (lane >> 2);   // + i*16
    const int scol = (lane & 3) * 8;
    const int wm = w >> 1, wn = w & 1;
    const int arow = wm * 64 + (lane & 15);
    const int brow = wn * 64 + (lane & 15);
    const int koff = (lane >> 4) * 8;

    for (int k0 = 0; k0 < KX; k0 += 32) {
        const ush *ab, *lb; size_t astr; int acol;
        if (k0 < Dm) { ab = xh; lb = xl; astr = Dm;  acol = k0; }
        else         { ab = Eh; lb = El; astr = 128; acol = k0 - Dm; }
        __syncthreads();
        #pragma unroll
        for (int i = 0; i < 2; ++i) {
            const int row = srow + i * 16;
            int rg = m0 + row; if (rg > NT - 1) rg = NT - 1;
            load16(ab + (size_t)rg * astr + acol + scol, &sAh[w*1024 + i*512]);
            load16(lb + (size_t)rg * astr + acol + scol, &sAl[w*1024 + i*512]);
            load16(Bh + (size_t)(n0 + row) * KX + k0 + scol, &sBh[w*1024 + i*512]);
            load16(Bl + (size_t)(n0 + row) * KX + k0 + scol, &sBl[w*1024 + i*512]);
        }
        __syncthreads();
        short8 ah[4], al[4], bh[4], bl[4];
        #pragma unroll
        for (int i = 0; i < 4; ++i) {
            ah[i] = *(const short8*)&sAh[(arow + i*16)*32 + koff];
            al[i] = *(const short8*)&sAl[(arow + i*16)*32 + koff];
            bh[i] = *(const short8*)&sBh[(brow + i*16)*32 + koff];
            bl[i] = *(const short8*)&sBl[(brow + i*16)*32 + koff];
        }
        #pragma unroll
        for (int mi = 0; mi < 4; ++mi)
            #pragma unroll
            for (int ni = 0; ni < 4; ++ni) {
                acc[mi][ni] = __builtin_amdgcn_mfma_f32_16x16x32_bf16(ah[mi], bh[ni], acc[mi][ni], 0, 0, 0);
                acc[mi][ni] = __builtin_amdgcn_mfma_f32_16x16x32_bf16(ah[mi], bl[ni], acc[mi][ni], 0, 0, 0);
                acc[mi][ni] = __builtin_amdgcn_mfma_f32_16x16x32_bf16(al[mi], bh[ni], acc[mi][ni], 0, 0, 0);
            }
    }

    #pragma unroll
    for (int mi = 0; mi < 4; ++mi) {
        #pragma unroll
        for (int ni = 0; ni < 4; ++ni) {
            const int col = n0 + wn*64 + ni*16 + (lane & 15);
            const float bsv = bias[col];
            const int rbase = m0 + wm*64 + mi*16 + (lane >> 4) * 4;
            #pragma unroll
            for (int r = 0; r < 4; ++r) {
                const int row = rbase + r;
                if (row < NT) y[(size_t)row * Dm + col] = (acc[mi][ni][r] + bsv) * scale;
            }
        }
    }
}

// -------------------------------------------------------------- attention ---
__global__ __launch_bounds__(256) void attn_kernel(
    const float* q, const float* __restrict__ k,
    const float* __restrict__ v, float* ctx)
{
    __shared__ float qs[32][68];
    __shared__ float kv[64][68];
    __shared__ float sc[32][264];
    const int qt = blockIdx.x;
    const int h  = blockIdx.y;
    const int b  = blockIdx.z;
    const int t  = threadIdx.x;
    const size_t base = (size_t)b * SQ * Dm + (size_t)h * HD;

    {
        const int d = t & 63;
        for (int r = t >> 6; r < 32; r += 4) {
            const int s = qt * 32 + r;
            qs[r][d] = (s < SQ) ? q[base + (size_t)s * Dm + d] : 0.f;
        }
    }
    const int qi = t >> 3, l8 = t & 7;
    for (int kt = 0; kt < 5; ++kt) {
        __syncthreads();
        {
            const int d = t & 63;
            for (int r = t >> 6; r < 64; r += 4) {
                const int s = kt * 64 + r;
                kv[r][d] = (s < SQ) ? k[base + (size_t)s * Dm + d] : 0.f;
            }
        }
        __syncthreads();
        for (int jj = l8; jj < 64; jj += 8) {
            const int j = kt * 64 + jj;
            if (j >= SQ) break;
            float s = 0.f;
            #pragma unroll
            for (int d = 0; d < 64; d += 4) {
                float4 a = *(const float4*)&qs[qi][d];
                float4 c = *(const float4*)&kv[jj][d];
                s += a.x * c.x + a.y * c.y + a.z * c.z + a.w * c.w;
            }
            sc[qi][j] = s;
        }
    }
    __syncthreads();
    {
        float m = -1e30f;
        for (int j = l8; j < SQ; j += 8) m = fmaxf(m, sc[qi][j]);
        for (int off = 1; off < 8; off <<= 1) m = fmaxf(m, __shfl_xor(m, off, 64));
        float l = 0.f;
        for (int j = l8; j < SQ; j += 8) { float e = __expf(sc[qi][j] - m); sc[qi][j] = e; l += e; }
        for (int off = 1; off < 8; off <<= 1) l += __shfl_xor(l, off, 64);
        const float inv = 1.f / l;
        for (int j = l8; j < SQ; j += 8) sc[qi][j] *= inv;
    }
    float acc[8] = {};
    const int d = t & 63, qg = (t >> 6) * 8;
    for (int vt = 0; vt < 5; ++vt) {
        __syncthreads();
        for (int r = t >> 6; r < 64; r += 4) {
            const int s = vt * 64 + r;
            kv[r][d] = (s < SQ) ? v[base + (size_t)s * Dm + d] : 0.f;
        }
        __syncthreads();
        const int jmax = (SQ - vt * 64) < 64 ? (SQ - vt * 64) : 64;
        for (int jj = 0; jj < jmax; ++jj) {
            const float vv = kv[jj][d];
            const int j = vt * 64 + jj;
            #pragma unroll
            for (int r = 0; r < 8; ++r) acc[r] += sc[qg + r][j] * vv;
        }
    }
    #pragma unroll
    for (int r = 0; r < 8; ++r) {
        const int s = qt * 32 + qg + r;
        if (s < SQ) ctx[base + (size_t)s * Dm + d] = acc[r];
    }
}

// ------------------------------------------------------------------ launch --
extern "C" void kernel_launch(void* const* d_in, const int* in_sizes, int n_in,
                              void* d_out, int out_size, void* d_ws, size_t ws_size,
                              hipStream_t stream)
{
    const float* x   = (const float*)d_in[0];
    const float* gw1 = (const float*)d_in[1];
    const float* gb1 = (const float*)d_in[2];
    const float* gw2 = (const float*)d_in[3];
    const float* gb2 = (const float*)d_in[4];
    const float *Wm[4], *U[4], *Sv[4], *Vv[4], *bias[4];
    for (int p = 0; p < 4; ++p) {
        Wm[p]   = (const float*)d_in[5 + p*5 + 0];
        U[p]    = (const float*)d_in[5 + p*5 + 1];
        Sv[p]   = (const float*)d_in[5 + p*5 + 2];
        Vv[p]   = (const float*)d_in[5 + p*5 + 3];
        bias[p] = (const float*)d_in[5 + p*5 + 4];
    }
    char* wsb   = (char*)d_ws;
    float* gates = (float*)wsb;           // 64 floats
    int*   idx   = (int*)(wsb + 256);     // 64 ints
    ush* p = (ush*)(wsb + 1024);
    ush* xh = p; p += (size_t)NT * Dm;
    ush* xl = p; p += (size_t)NT * Dm;
    ush *eh[4], *el[4];
    for (int i = 0; i < 4; ++i) { eh[i] = p; p += (size_t)NT * 128; el[i] = p; p += (size_t)NT * 128; }
    ush *Bh[4], *Bl[4];
    for (int i = 0; i < 4; ++i) { Bh[i] = p; p += (size_t)1024 * KX; Bl[i] = p; p += (size_t)1024 * KX; }
    float* qb = (float*)p;
    float* kb = qb + (size_t)NT * Dm;
    float* vb = kb + (size_t)NT * Dm;
    float* cb = qb;   // ctx aliases q: each attn block overwrites exactly the q it consumed

    gating_kernel<<<Bb, 256, 0, stream>>>(x, gw1, gb1, gw2, gb2, gates, idx);
    convx_kernel<<<NT, 256, 0, stream>>>(x, xh, xl);
    ext_kernel<<<NT, 256, 0, stream>>>(x,
        Vv[0], Sv[0], eh[0], el[0],
        Vv[1], Sv[1], eh[1], el[1],
        Vv[2], Sv[2], eh[2], el[2], gates, idx, 3);
    for (int i = 0; i < 4; ++i)
        convB_kernel<<<1152, 256, 0, stream>>>(Wm[i], U[i], Bh[i], Bl[i]);

    gemm_mfma<<<dim3(8, 65, 3), 256, 0, stream>>>(
        xh, xl, eh[0], el[0], eh[1], el[1], eh[2], el[2],
        Bh[0], Bl[0], Bh[1], Bl[1], Bh[2], Bl[2],
        bias[0], bias[1], bias[2], qb, kb, vb, 0.125f);

    attn_kernel<<<dim3(9, 16, Bb), 256, 0, stream>>>(qb, kb, vb, cb);

    convx_kernel<<<NT, 256, 0, stream>>>(cb, xh, xl);   // reuse x buffers for ctx
    ext_kernel<<<NT, 256, 0, stream>>>(cb,
        Vv[3], Sv[3], eh[3], el[3],
        nullptr, nullptr, nullptr, nullptr,
        nullptr, nullptr, nullptr, nullptr, gates, idx, 1);

    gemm_mfma<<<dim3(8, 65, 1), 256, 0, stream>>>(
        xh, xl, eh[3], el[3], eh[3], el[3], eh[3], el[3],
        Bh[3], Bl[3], Bh[3], Bl[3], Bh[3], Bl[3],
        bias[3], bias[3], bias[3], (float*)d_out, (float*)d_out, (float*)d_out, 1.0f);
}

// Round 3
// 1205.619 us; speedup vs baseline: 2.6803x; 1.5022x over previous
//
#include <hip/hip_runtime.h>
#include <math.h>

#define Bb   32
#define SQ   257
#define Dm   1024
#define HD   64
#define Ee   8
#define Rr   16
#define GHh  256
#define NT   (Bb*SQ)   // 8224
#define KX   1152      // 1024 + E*R extension
#define LDP  72        // padded LDS row (64 ush + 8)

typedef unsigned short ush;
typedef __attribute__((ext_vector_type(8))) short short8;
typedef __attribute__((ext_vector_type(4))) float floatx4;
typedef __attribute__((ext_vector_type(4))) unsigned short ushort4v;

__device__ __forceinline__ ush f2bf(float f) {
    union { float f; unsigned u; } a; a.f = f;
    unsigned r = a.u + 0x7fff + ((a.u >> 16) & 1);   // RNE
    return (ush)(r >> 16);
}
__device__ __forceinline__ float bf2f(ush u) {
    union { unsigned u; float f; } a; a.u = ((unsigned)u) << 16; return a.f;
}
__device__ __forceinline__ void load16(const ush* g, ush* l) {
    __builtin_amdgcn_global_load_lds(
        (const __attribute__((address_space(1))) unsigned int*)g,
        (__attribute__((address_space(3))) unsigned int*)l,
        16, 0, 0);
}

// ----------------------------------------------------- gating stage A: pool -
__global__ __launch_bounds__(256) void pool_kernel(
    const float* __restrict__ x, float* __restrict__ pp)
{
    const int c = blockIdx.x, b = blockIdx.y, t = threadIdx.x;
    const int s0 = c * 16, s1 = (c == 15) ? SQ : s0 + 16;
    float4 acc = make_float4(0.f, 0.f, 0.f, 0.f);
    const float* xp = x + ((size_t)b * SQ + s0) * Dm + t * 4;
    for (int s = s0; s < s1; ++s, xp += Dm) {
        float4 v = *(const float4*)xp;
        acc.x += v.x; acc.y += v.y; acc.z += v.z; acc.w += v.w;
    }
    *(float4*)(pp + ((size_t)b * 16 + c) * Dm + t * 4) = acc;
}

// ----------------------------------------------- gating stage B: MLP + top2 -
__global__ __launch_bounds__(256) void gating2_kernel(
    const float* __restrict__ pp, const float* __restrict__ gw1,
    const float* __restrict__ gb1, const float* __restrict__ gw2,
    const float* __restrict__ gb2,
    float* __restrict__ gates, int* __restrict__ idx)
{
    __shared__ float pooled[Dm];
    __shared__ float hbuf[GHh];
    __shared__ float logits[Ee];
    const int b = blockIdx.x, t = threadIdx.x;
    const int w = t >> 6, lane = t & 63;

    float4 acc = make_float4(0.f, 0.f, 0.f, 0.f);
    for (int c = 0; c < 16; ++c) {
        float4 v = *(const float4*)(pp + ((size_t)b * 16 + c) * Dm + t * 4);
        acc.x += v.x; acc.y += v.y; acc.z += v.z; acc.w += v.w;
    }
    const float sc = 1.0f / SQ;
    pooled[t*4+0] = acc.x * sc; pooled[t*4+1] = acc.y * sc;
    pooled[t*4+2] = acc.z * sc; pooled[t*4+3] = acc.w * sc;
    __syncthreads();

    for (int oi = 0; oi < 64; ++oi) {
        const int o = w * 64 + oi;
        const float* g = gw1 + (size_t)o * Dm;
        float s = 0.f;
        #pragma unroll
        for (int i = 0; i < 16; ++i) s += pooled[lane + i*64] * g[lane + i*64];
        for (int off = 32; off > 0; off >>= 1) s += __shfl_down(s, off, 64);
        if (lane == 0) hbuf[o] = fmaxf(s + gb1[o], 0.f);
    }
    __syncthreads();
    if (t < Ee) {
        const float* g = gw2 + t * GHh;
        float s = 0.f;
        for (int j = 0; j < GHh; ++j) s += hbuf[j] * g[j];
        logits[t] = s + gb2[t];
    }
    __syncthreads();
    if (t == 0) {
        int i1 = 0; float v1 = logits[0];
        for (int e = 1; e < Ee; ++e) if (logits[e] > v1) { v1 = logits[e]; i1 = e; }
        int i2 = 0; float v2 = -1e30f;
        for (int e = 0; e < Ee; ++e) if (e != i1 && logits[e] > v2) { v2 = logits[e]; i2 = e; }
        float e2 = __expf(v2 - v1);
        float inv = 1.f / (1.f + e2);
        gates[b*2+0] = inv; gates[b*2+1] = e2 * inv;
        idx[b*2+0] = i1; idx[b*2+1] = i2;
    }
}

// ------------------------------------------------ fp32 -> split bf16 (rows) -
__global__ __launch_bounds__(256) void convx_kernel(
    const float* __restrict__ x, ush* __restrict__ xh, ush* __restrict__ xl)
{
    const int m = blockIdx.x, t = threadIdx.x;
    float4 v = *(const float4*)(x + (size_t)m * Dm + t * 4);
    ushort4v hv, lv;
    hv.x = f2bf(v.x); lv.x = f2bf(v.x - bf2f(hv.x));
    hv.y = f2bf(v.y); lv.y = f2bf(v.y - bf2f(hv.y));
    hv.z = f2bf(v.z); lv.z = f2bf(v.z - bf2f(hv.z));
    hv.w = f2bf(v.w); lv.w = f2bf(v.w - bf2f(hv.w));
    *(ushort4v*)(xh + (size_t)m * Dm + t * 4) = hv;
    *(ushort4v*)(xl + (size_t)m * Dm + t * 4) = lv;
}

// --------------------------------- W,U -> split bf16 B matrix (1024 x 1152) -
__global__ __launch_bounds__(256) void convB_kernel(
    const float* __restrict__ W, const float* __restrict__ U,
    ush* __restrict__ Bh, ush* __restrict__ Bl)
{
    const int i = blockIdx.x * 256 + threadIdx.x;
    const int n = i / 288, c4 = i % 288, col = c4 * 4;
    float4 v;
    if (col < Dm) {
        v = *(const float4*)(W + (size_t)n * Dm + col);
    } else {
        int ec = col - Dm, e = ec >> 4, r = ec & 15;
        v = *(const float4*)(U + ((size_t)(e * Dm + n)) * Rr + r);
    }
    ushort4v hv, lv;
    hv.x = f2bf(v.x); lv.x = f2bf(v.x - bf2f(hv.x));
    hv.y = f2bf(v.y); lv.y = f2bf(v.y - bf2f(hv.y));
    hv.z = f2bf(v.z); lv.z = f2bf(v.z - bf2f(hv.z));
    hv.w = f2bf(v.w); lv.w = f2bf(v.w - bf2f(hv.w));
    *(ushort4v*)(Bh + (size_t)n * KX + col) = hv;
    *(ushort4v*)(Bl + (size_t)n * KX + col) = lv;
}

// -------------------- expert-subspace ext columns: g*S*(x.V) as split bf16 --
// input read from split-bf16 (xh+xl reconstructs fp32 to ~4e-6)
__global__ __launch_bounds__(256) void ext_kernel(
    const ush* __restrict__ xh, const ush* __restrict__ xl,
    const float* __restrict__ V0, const float* __restrict__ S0, ush* __restrict__ h0, ush* __restrict__ l0,
    const float* __restrict__ V1, const float* __restrict__ S1, ush* __restrict__ h1, ush* __restrict__ l1,
    const float* __restrict__ V2, const float* __restrict__ S2, ush* __restrict__ h2, ush* __restrict__ l2,
    const float* __restrict__ gates, const int* __restrict__ idx, int nproj)
{
    __shared__ float xrow[Dm];
    const int m = blockIdx.x, b = m / SQ, t = threadIdx.x;
    const int lane = t & 63, wave = t >> 6;

    for (int d = t; d < Dm; d += 256)
        xrow[d] = bf2f(xh[(size_t)m * Dm + d]) + bf2f(xl[(size_t)m * Dm + d]);
    for (int p = 0; p < nproj; ++p) {
        ush* hh = p == 0 ? h0 : p == 1 ? h1 : h2;
        ush* ll = p == 0 ? l0 : p == 1 ? l1 : l2;
        for (int c = t; c < 128; c += 256) {
            hh[(size_t)m * 128 + c] = 0; ll[(size_t)m * 128 + c] = 0;
        }
    }
    __syncthreads();
    const int e0 = idx[b*2+0], e1 = idx[b*2+1];
    const float g0 = gates[b*2+0], g1 = gates[b*2+1];
    const int ndot = nproj * 32;
    for (int j = wave; j < ndot; j += 4) {
        const int p = j >> 5, jj = j & 31, kk = jj >> 4, r = jj & 15;
        const float* V  = p == 0 ? V0 : p == 1 ? V1 : V2;
        const float* Sp = p == 0 ? S0 : p == 1 ? S1 : S2;
        ush* hh = p == 0 ? h0 : p == 1 ? h1 : h2;
        ush* ll = p == 0 ? l0 : p == 1 ? l1 : l2;
        const int e = kk ? e1 : e0;
        const float g = kk ? g1 : g0;
        const float* vr = V + ((size_t)e * Rr + r) * Dm;
        float s = 0.f;
        for (int d = lane; d < Dm; d += 64) s += xrow[d] * vr[d];
        for (int off = 32; off > 0; off >>= 1) s += __shfl_down(s, off, 64);
        if (lane == 0) {
            float val = s * g * Sp[e * Rr + r];
            ush hv = f2bf(val);
            hh[(size_t)m * 128 + e * 16 + r] = hv;
            ll[(size_t)m * 128 + e * 16 + r] = f2bf(val - bf2f(hv));
        }
    }
}

// -------------------------------- split-bf16 MFMA GEMM, K=1152 (1024+ext) ---
__global__ __launch_bounds__(256) void gemm_mfma(
    const ush* __restrict__ xh, const ush* __restrict__ xl,
    const ush* __restrict__ e0h, const ush* __restrict__ e0l,
    const ush* __restrict__ e1h, const ush* __restrict__ e1l,
    const ush* __restrict__ e2h, const ush* __restrict__ e2l,
    const ush* __restrict__ B0h, const ush* __restrict__ B0l,
    const ush* __restrict__ B1h, const ush* __restrict__ B1l,
    const ush* __restrict__ B2h, const ush* __restrict__ B2l,
    const float* __restrict__ b0, const float* __restrict__ b1, const float* __restrict__ b2,
    float* __restrict__ y0, float* __restrict__ y1, float* __restrict__ y2,
    float scale0)
{
    const int z = blockIdx.z;
    const ush* Eh = z == 0 ? e0h : z == 1 ? e1h : e2h;
    const ush* El = z == 0 ? e0l : z == 1 ? e1l : e2l;
    const ush* Bh = z == 0 ? B0h : z == 1 ? B1h : B2h;
    const ush* Bl = z == 0 ? B0l : z == 1 ? B1l : B2l;
    const float* bias = z == 0 ? b0 : z == 1 ? b1 : b2;
    float* y = z == 0 ? y0 : z == 1 ? y1 : y2;
    const float scale = z == 0 ? scale0 : 1.0f;

    __shared__ ush sAh[128*32], sAl[128*32], sBh[128*32], sBl[128*32];
    const int t = threadIdx.x, lane = t & 63, w = t >> 6;
    const int m0 = blockIdx.y * 128, n0 = blockIdx.x * 128;

    floatx4 acc[4][4] = {};

    const int srow = w * 32 + (lane >> 2);
    const int scol = (lane & 3) * 8;
    const int wm = w >> 1, wn = w & 1;
    const int arow = wm * 64 + (lane & 15);
    const int brow = wn * 64 + (lane & 15);
    const int koff = (lane >> 4) * 8;

    for (int k0 = 0; k0 < KX; k0 += 32) {
        const ush *ab, *lb; size_t astr; int acol;
        if (k0 < Dm) { ab = xh; lb = xl; astr = Dm;  acol = k0; }
        else         { ab = Eh; lb = El; astr = 128; acol = k0 - Dm; }
        __syncthreads();
        #pragma unroll
        for (int i = 0; i < 2; ++i) {
            const int row = srow + i * 16;
            int rg = m0 + row; if (rg > NT - 1) rg = NT - 1;
            load16(ab + (size_t)rg * astr + acol + scol, &sAh[w*1024 + i*512]);
            load16(lb + (size_t)rg * astr + acol + scol, &sAl[w*1024 + i*512]);
            load16(Bh + (size_t)(n0 + row) * KX + k0 + scol, &sBh[w*1024 + i*512]);
            load16(Bl + (size_t)(n0 + row) * KX + k0 + scol, &sBl[w*1024 + i*512]);
        }
        __syncthreads();
        short8 ah[4], al[4], bh[4], bl[4];
        #pragma unroll
        for (int i = 0; i < 4; ++i) {
            ah[i] = *(const short8*)&sAh[(arow + i*16)*32 + koff];
            al[i] = *(const short8*)&sAl[(arow + i*16)*32 + koff];
            bh[i] = *(const short8*)&sBh[(brow + i*16)*32 + koff];
            bl[i] = *(const short8*)&sBl[(brow + i*16)*32 + koff];
        }
        #pragma unroll
        for (int mi = 0; mi < 4; ++mi)
            #pragma unroll
            for (int ni = 0; ni < 4; ++ni) {
                acc[mi][ni] = __builtin_amdgcn_mfma_f32_16x16x32_bf16(ah[mi], bh[ni], acc[mi][ni], 0, 0, 0);
                acc[mi][ni] = __builtin_amdgcn_mfma_f32_16x16x32_bf16(ah[mi], bl[ni], acc[mi][ni], 0, 0, 0);
                acc[mi][ni] = __builtin_amdgcn_mfma_f32_16x16x32_bf16(al[mi], bh[ni], acc[mi][ni], 0, 0, 0);
            }
    }

    #pragma unroll
    for (int mi = 0; mi < 4; ++mi) {
        #pragma unroll
        for (int ni = 0; ni < 4; ++ni) {
            const int col = n0 + wn*64 + ni*16 + (lane & 15);
            const float bsv = bias[col];
            const int rbase = m0 + wm*64 + mi*16 + (lane >> 4) * 4;
            #pragma unroll
            for (int r = 0; r < 4; ++r) {
                const int row = rbase + r;
                if (row < NT) y[(size_t)row * Dm + col] = (acc[mi][ni][r] + bsv) * scale;
            }
        }
    }
}

// ------------------------------------- MFMA flash attention (bf16 splits) ---
// block: one (b,h), 64 q rows; 4 waves x 16 q rows. writes ctx as split bf16.
__global__ __launch_bounds__(256) void attn_mfma(
    const float* __restrict__ q, const float* __restrict__ k,
    const float* __restrict__ v, ush* __restrict__ ch, ush* __restrict__ cl)
{
    __shared__ ush sKh[64*LDP], sKl[64*LDP], sVt[64*LDP];
    __shared__ ush sP[4][16*LDP];
    const int qt = blockIdx.x, h = blockIdx.y, b = blockIdx.z;
    const int t = threadIdx.x, lane = t & 63, w = t >> 6;
    const int quad = lane >> 4, l16 = lane & 15;
    const size_t base = (size_t)b * SQ * Dm + (size_t)h * HD;

    // stage Q tile (rows qt*64..+63, clamped) into sKh/sKl
    #pragma unroll
    for (int i = 0; i < 4; ++i) {
        const int c = t + i * 256;
        const int row = c >> 4, c4 = c & 15;
        int s = qt * 64 + row; if (s > SQ - 1) s = SQ - 1;
        float4 vq = *(const float4*)(q + base + (size_t)s * Dm + c4 * 4);
        ushort4v hv, lv;
        hv.x = f2bf(vq.x); lv.x = f2bf(vq.x - bf2f(hv.x));
        hv.y = f2bf(vq.y); lv.y = f2bf(vq.y - bf2f(hv.y));
        hv.z = f2bf(vq.z); lv.z = f2bf(vq.z - bf2f(hv.z));
        hv.w = f2bf(vq.w); lv.w = f2bf(vq.w - bf2f(hv.w));
        *(ushort4v*)&sKh[row*LDP + c4*4] = hv;
        *(ushort4v*)&sKl[row*LDP + c4*4] = lv;
    }
    __syncthreads();
    short8 qh[2], ql[2];
    #pragma unroll
    for (int s = 0; s < 2; ++s) {
        qh[s] = *(const short8*)&sKh[(w*16 + l16)*LDP + s*32 + quad*8];
        ql[s] = *(const short8*)&sKl[(w*16 + l16)*LDP + s*32 + quad*8];
    }

    floatx4 O[4] = {};
    float mrow[4], lrow[4];
    #pragma unroll
    for (int r = 0; r < 4; ++r) { mrow[r] = -1e30f; lrow[r] = 0.f; }
    const bool active = (qt * 64 + w * 16) < SQ;

    for (int kt = 0; kt < 5; ++kt) {
        __syncthreads();
        #pragma unroll
        for (int i = 0; i < 4; ++i) {
            const int c = t + i * 256;
            const int row = c >> 4, c4 = c & 15;
            const int s = kt * 64 + row;
            float4 kv4 = make_float4(0.f,0.f,0.f,0.f);
            float4 vv4 = make_float4(0.f,0.f,0.f,0.f);
            if (s < SQ) {
                kv4 = *(const float4*)(k + base + (size_t)s * Dm + c4 * 4);
                vv4 = *(const float4*)(v + base + (size_t)s * Dm + c4 * 4);
            }
            ushort4v hv, lv;
            hv.x = f2bf(kv4.x); lv.x = f2bf(kv4.x - bf2f(hv.x));
            hv.y = f2bf(kv4.y); lv.y = f2bf(kv4.y - bf2f(hv.y));
            hv.z = f2bf(kv4.z); lv.z = f2bf(kv4.z - bf2f(hv.z));
            hv.w = f2bf(kv4.w); lv.w = f2bf(kv4.w - bf2f(hv.w));
            *(ushort4v*)&sKh[row*LDP + c4*4] = hv;
            *(ushort4v*)&sKl[row*LDP + c4*4] = lv;
            sVt[(c4*4+0)*LDP + row] = f2bf(vv4.x);
            sVt[(c4*4+1)*LDP + row] = f2bf(vv4.y);
            sVt[(c4*4+2)*LDP + row] = f2bf(vv4.z);
            sVt[(c4*4+3)*LDP + row] = f2bf(vv4.w);
        }
        __syncthreads();
        if (!active) continue;

        floatx4 S[4] = {};
        #pragma unroll
        for (int ni = 0; ni < 4; ++ni)
            #pragma unroll
            for (int s = 0; s < 2; ++s) {
                short8 kh = *(const short8*)&sKh[(ni*16 + l16)*LDP + s*32 + quad*8];
                short8 kl = *(const short8*)&sKl[(ni*16 + l16)*LDP + s*32 + quad*8];
                S[ni] = __builtin_amdgcn_mfma_f32_16x16x32_bf16(qh[s], kh, S[ni], 0, 0, 0);
                S[ni] = __builtin_amdgcn_mfma_f32_16x16x32_bf16(qh[s], kl, S[ni], 0, 0, 0);
                S[ni] = __builtin_amdgcn_mfma_f32_16x16x32_bf16(ql[s], kh, S[ni], 0, 0, 0);
            }
        #pragma unroll
        for (int ni = 0; ni < 4; ++ni) {
            const int jg = kt * 64 + ni * 16 + l16;
            if (jg >= SQ) { S[ni][0] = -1e30f; S[ni][1] = -1e30f; S[ni][2] = -1e30f; S[ni][3] = -1e30f; }
        }
        float mnew[4], alpha[4];
        #pragma unroll
        for (int r = 0; r < 4; ++r) {
            float mx = fmaxf(fmaxf(S[0][r], S[1][r]), fmaxf(S[2][r], S[3][r]));
            #pragma unroll
            for (int off = 1; off < 16; off <<= 1) mx = fmaxf(mx, __shfl_xor(mx, off, 64));
            mnew[r] = fmaxf(mrow[r], mx);
            alpha[r] = __expf(mrow[r] - mnew[r]);
            mrow[r] = mnew[r];
        }
        float p[4][4], rs[4];
        #pragma unroll
        for (int r = 0; r < 4; ++r) rs[r] = 0.f;
        #pragma unroll
        for (int ni = 0; ni < 4; ++ni)
            #pragma unroll
            for (int r = 0; r < 4; ++r) {
                float e = __expf(S[ni][r] - mnew[r]);
                p[ni][r] = e; rs[r] += e;
            }
        #pragma unroll
        for (int r = 0; r < 4; ++r) {
            #pragma unroll
            for (int off = 1; off < 16; off <<= 1) rs[r] += __shfl_xor(rs[r], off, 64);
            lrow[r] = lrow[r] * alpha[r] + rs[r];
        }
        #pragma unroll
        for (int ni = 0; ni < 4; ++ni)
            #pragma unroll
            for (int r = 0; r < 4; ++r) O[ni][r] *= alpha[r];
        #pragma unroll
        for (int ni = 0; ni < 4; ++ni)
            #pragma unroll
            for (int r = 0; r < 4; ++r)
                sP[w][(quad*4 + r)*LDP + ni*16 + l16] = f2bf(p[ni][r]);
        #pragma unroll
        for (int ni = 0; ni < 4; ++ni)
            #pragma unroll
            for (int s = 0; s < 2; ++s) {
                short8 a  = *(const short8*)&sP[w][l16*LDP + s*32 + quad*8];
                short8 bb = *(const short8*)&sVt[(ni*16 + l16)*LDP + s*32 + quad*8];
                O[ni] = __builtin_amdgcn_mfma_f32_16x16x32_bf16(a, bb, O[ni], 0, 0, 0);
            }
    }

    if (active) {
        #pragma unroll
        for (int ni = 0; ni < 4; ++ni) {
            const int col = h * HD + ni * 16 + l16;
            #pragma unroll
            for (int r = 0; r < 4; ++r) {
                const int s = qt * 64 + w * 16 + quad * 4 + r;
                if (s < SQ) {
                    const float val = O[ni][r] / lrow[r];
                    const size_t m = (size_t)b * SQ + s;
                    const ush hv = f2bf(val);
                    ch[m * Dm + col] = hv;
                    cl[m * Dm + col] = f2bf(val - bf2f(hv));
                }
            }
        }
    }
}

// ------------------------------------------------------------------ launch --
extern "C" void kernel_launch(void* const* d_in, const int* in_sizes, int n_in,
                              void* d_out, int out_size, void* d_ws, size_t ws_size,
                              hipStream_t stream)
{
    const float* x   = (const float*)d_in[0];
    const float* gw1 = (const float*)d_in[1];
    const float* gb1 = (const float*)d_in[2];
    const float* gw2 = (const float*)d_in[3];
    const float* gb2 = (const float*)d_in[4];
    const float *Wm[4], *U[4], *Sv[4], *Vv[4], *bias[4];
    for (int p = 0; p < 4; ++p) {
        Wm[p]   = (const float*)d_in[5 + p*5 + 0];
        U[p]    = (const float*)d_in[5 + p*5 + 1];
        Sv[p]   = (const float*)d_in[5 + p*5 + 2];
        Vv[p]   = (const float*)d_in[5 + p*5 + 3];
        bias[p] = (const float*)d_in[5 + p*5 + 4];
    }
    char* wsb   = (char*)d_ws;
    float* gates = (float*)wsb;           // 64 floats
    int*   idx   = (int*)(wsb + 256);     // 64 ints
    float* pool  = (float*)(wsb + 1024);  // 32*16*1024 floats = 2 MB
    ush* p = (ush*)(wsb + 1024 + (size_t)Bb * 16 * Dm * 4);
    ush* xh = p; p += (size_t)NT * Dm;
    ush* xl = p; p += (size_t)NT * Dm;
    ush *eh[4], *el[4];
    for (int i = 0; i < 4; ++i) { eh[i] = p; p += (size_t)NT * 128; el[i] = p; p += (size_t)NT * 128; }
    ush *Bh[4], *Bl[4];
    for (int i = 0; i < 4; ++i) { Bh[i] = p; p += (size_t)1024 * KX; Bl[i] = p; p += (size_t)1024 * KX; }
    float* qb = (float*)p;
    float* kb = qb + (size_t)NT * Dm;
    float* vb = kb + (size_t)NT * Dm;

    pool_kernel<<<dim3(16, Bb), 256, 0, stream>>>(x, pool);
    gating2_kernel<<<Bb, 256, 0, stream>>>(pool, gw1, gb1, gw2, gb2, gates, idx);
    convx_kernel<<<NT, 256, 0, stream>>>(x, xh, xl);
    ext_kernel<<<NT, 256, 0, stream>>>(xh, xl,
        Vv[0], Sv[0], eh[0], el[0],
        Vv[1], Sv[1], eh[1], el[1],
        Vv[2], Sv[2], eh[2], el[2], gates, idx, 3);
    for (int i = 0; i < 4; ++i)
        convB_kernel<<<1152, 256, 0, stream>>>(Wm[i], U[i], Bh[i], Bl[i]);

    gemm_mfma<<<dim3(8, 65, 3), 256, 0, stream>>>(
        xh, xl, eh[0], el[0], eh[1], el[1], eh[2], el[2],
        Bh[0], Bl[0], Bh[1], Bl[1], Bh[2], Bl[2],
        bias[0], bias[1], bias[2], qb, kb, vb, 0.125f);

    // attention writes ctx directly as split-bf16 into xh/xl (x no longer needed)
    attn_mfma<<<dim3(5, 16, Bb), 256, 0, stream>>>(qb, kb, vb, xh, xl);

    ext_kernel<<<NT, 256, 0, stream>>>(xh, xl,
        Vv[3], Sv[3], eh[3], el[3],
        Vv[3], Sv[3], eh[3], el[3],
        Vv[3], Sv[3], eh[3], el[3], gates, idx, 1);

    gemm_mfma<<<dim3(8, 65, 1), 256, 0, stream>>>(
        xh, xl, eh[3], el[3], eh[3], el[3], eh[3], el[3],
        Bh[3], Bl[3], Bh[3], Bl[3], Bh[3], Bl[3],
        bias[3], bias[3], bias[3], (float*)d_out, (float*)d_out, (float*)d_out, 1.0f);
}

// Round 4
// 694.079 us; speedup vs baseline: 4.6557x; 1.7370x over previous
//
#include <hip/hip_runtime.h>
#include <math.h>

#define Bb   32
#define SQ   257
#define Dm   1024
#define HD   64
#define Ee   8
#define Rr   16
#define GHh  256
#define NT   (Bb*SQ)   // 8224
#define KX   1152      // 1024 + E*R extension
#define LDP  72        // padded LDS row (64 ush + 8)

typedef unsigned short ush;
typedef __attribute__((ext_vector_type(8))) short short8;
typedef __attribute__((ext_vector_type(4))) float floatx4;
typedef __attribute__((ext_vector_type(4))) unsigned short ushort4v;

__device__ __forceinline__ ush f2bf(float f) {
    union { float f; unsigned u; } a; a.f = f;
    unsigned r = a.u + 0x7fff + ((a.u >> 16) & 1);   // RNE
    return (ush)(r >> 16);
}
__device__ __forceinline__ float bf2f(ush u) {
    union { unsigned u; float f; } a; a.u = ((unsigned)u) << 16; return a.f;
}
__device__ __forceinline__ void load16(const ush* g, ush* l) {
    __builtin_amdgcn_global_load_lds(
        (const __attribute__((address_space(1))) unsigned int*)g,
        (__attribute__((address_space(3))) unsigned int*)l,
        16, 0, 0);
}

// ----------------------------------------------------- gating stage A: pool -
__global__ __launch_bounds__(256) void pool_kernel(
    const float* __restrict__ x, float* __restrict__ pp)
{
    const int c = blockIdx.x, b = blockIdx.y, t = threadIdx.x;
    const int s0 = c * 16, s1 = (c == 15) ? SQ : s0 + 16;
    float4 acc = make_float4(0.f, 0.f, 0.f, 0.f);
    const float* xp = x + ((size_t)b * SQ + s0) * Dm + t * 4;
    for (int s = s0; s < s1; ++s, xp += Dm) {
        float4 v = *(const float4*)xp;
        acc.x += v.x; acc.y += v.y; acc.z += v.z; acc.w += v.w;
    }
    *(float4*)(pp + ((size_t)b * 16 + c) * Dm + t * 4) = acc;
}

// ----------------------------------------------- gating stage B: MLP + top2 -
__global__ __launch_bounds__(256) void gating2_kernel(
    const float* __restrict__ pp, const float* __restrict__ gw1,
    const float* __restrict__ gb1, const float* __restrict__ gw2,
    const float* __restrict__ gb2,
    float* __restrict__ gates, int* __restrict__ idx)
{
    __shared__ float pooled[Dm];
    __shared__ float hbuf[GHh];
    __shared__ float logits[Ee];
    const int b = blockIdx.x, t = threadIdx.x;
    const int w = t >> 6, lane = t & 63;

    float4 acc = make_float4(0.f, 0.f, 0.f, 0.f);
    for (int c = 0; c < 16; ++c) {
        float4 v = *(const float4*)(pp + ((size_t)b * 16 + c) * Dm + t * 4);
        acc.x += v.x; acc.y += v.y; acc.z += v.z; acc.w += v.w;
    }
    const float sc = 1.0f / SQ;
    pooled[t*4+0] = acc.x * sc; pooled[t*4+1] = acc.y * sc;
    pooled[t*4+2] = acc.z * sc; pooled[t*4+3] = acc.w * sc;
    __syncthreads();

    for (int oi = 0; oi < 64; ++oi) {
        const int o = w * 64 + oi;
        const float* g = gw1 + (size_t)o * Dm;
        float s = 0.f;
        #pragma unroll
        for (int i = 0; i < 16; ++i) s += pooled[lane + i*64] * g[lane + i*64];
        for (int off = 32; off > 0; off >>= 1) s += __shfl_down(s, off, 64);
        if (lane == 0) hbuf[o] = fmaxf(s + gb1[o], 0.f);
    }
    __syncthreads();
    if (t < Ee) {
        const float* g = gw2 + t * GHh;
        float s = 0.f;
        for (int j = 0; j < GHh; ++j) s += hbuf[j] * g[j];
        logits[t] = s + gb2[t];
    }
    __syncthreads();
    if (t == 0) {
        int i1 = 0; float v1 = logits[0];
        for (int e = 1; e < Ee; ++e) if (logits[e] > v1) { v1 = logits[e]; i1 = e; }
        int i2 = 0; float v2 = -1e30f;
        for (int e = 0; e < Ee; ++e) if (e != i1 && logits[e] > v2) { v2 = logits[e]; i2 = e; }
        float e2 = __expf(v2 - v1);
        float inv = 1.f / (1.f + e2);
        gates[b*2+0] = inv; gates[b*2+1] = e2 * inv;
        idx[b*2+0] = i1; idx[b*2+1] = i2;
    }
}

// ------------------------------------------------ fp32 -> split bf16 (rows) -
__global__ __launch_bounds__(256) void convx_kernel(
    const float* __restrict__ x, ush* __restrict__ xh, ush* __restrict__ xl)
{
    const int m = blockIdx.x, t = threadIdx.x;
    float4 v = *(const float4*)(x + (size_t)m * Dm + t * 4);
    ushort4v hv, lv;
    hv.x = f2bf(v.x); lv.x = f2bf(v.x - bf2f(hv.x));
    hv.y = f2bf(v.y); lv.y = f2bf(v.y - bf2f(hv.y));
    hv.z = f2bf(v.z); lv.z = f2bf(v.z - bf2f(hv.z));
    hv.w = f2bf(v.w); lv.w = f2bf(v.w - bf2f(hv.w));
    *(ushort4v*)(xh + (size_t)m * Dm + t * 4) = hv;
    *(ushort4v*)(xl + (size_t)m * Dm + t * 4) = lv;
}

// --------------------------------- W,U -> split bf16 B matrix (1024 x 1152) -
__global__ __launch_bounds__(256) void convB_kernel(
    const float* __restrict__ W, const float* __restrict__ U,
    ush* __restrict__ Bh, ush* __restrict__ Bl)
{
    const int i = blockIdx.x * 256 + threadIdx.x;
    const int n = i / 288, c4 = i % 288, col = c4 * 4;
    float4 v;
    if (col < Dm) {
        v = *(const float4*)(W + (size_t)n * Dm + col);
    } else {
        int ec = col - Dm, e = ec >> 4, r = ec & 15;
        v = *(const float4*)(U + ((size_t)(e * Dm + n)) * Rr + r);
    }
    ushort4v hv, lv;
    hv.x = f2bf(v.x); lv.x = f2bf(v.x - bf2f(hv.x));
    hv.y = f2bf(v.y); lv.y = f2bf(v.y - bf2f(hv.y));
    hv.z = f2bf(v.z); lv.z = f2bf(v.z - bf2f(hv.z));
    hv.w = f2bf(v.w); lv.w = f2bf(v.w - bf2f(hv.w));
    *(ushort4v*)(Bh + (size_t)n * KX + col) = hv;
    *(ushort4v*)(Bl + (size_t)n * KX + col) = lv;
}

// ------------------------------------------------- V -> split bf16 (4 proj) -
__global__ __launch_bounds__(256) void convV_kernel(
    const float* __restrict__ V0, const float* __restrict__ V1,
    const float* __restrict__ V2, const float* __restrict__ V3,
    ush* __restrict__ Vh, ush* __restrict__ Vl)
{
    const int p = blockIdx.y;
    const float* V = p == 0 ? V0 : p == 1 ? V1 : p == 2 ? V2 : V3;
    const size_t i = ((size_t)blockIdx.x * 256 + threadIdx.x) * 4; // < 131072
    float4 v = *(const float4*)(V + i);
    ushort4v hv, lv;
    hv.x = f2bf(v.x); lv.x = f2bf(v.x - bf2f(hv.x));
    hv.y = f2bf(v.y); lv.y = f2bf(v.y - bf2f(hv.y));
    hv.z = f2bf(v.z); lv.z = f2bf(v.z - bf2f(hv.z));
    hv.w = f2bf(v.w); lv.w = f2bf(v.w - bf2f(hv.w));
    const size_t off = (size_t)p * Ee * Rr * Dm + i;
    *(ushort4v*)(Vh + off) = hv;
    *(ushort4v*)(Vl + off) = lv;
}

// --------------- ext as MFMA GEMM: xvs[s,j] = gS * (x[s,:] . Vsel[j,:]) -----
// grid (5 m-tiles, Bb). 64-row M tile, N = NP*32 (2 experts x 16 ranks).
template<int NP>
__global__ __launch_bounds__(256) void ext_gemm(
    const ush* __restrict__ xh, const ush* __restrict__ xl,
    const ush* __restrict__ Vh, const ush* __restrict__ Vl,   // [4][128][1024]
    const float* __restrict__ S0, const float* __restrict__ S1,
    const float* __restrict__ S2,
    ush* __restrict__ o0h, ush* __restrict__ o0l,
    ush* __restrict__ o1h, ush* __restrict__ o1l,
    ush* __restrict__ o2h, ush* __restrict__ o2l,
    const float* __restrict__ gates, const int* __restrict__ idx, int pbase)
{
    __shared__ ush sAh[64*32], sAl[64*32], sBh[NP*32*32], sBl[NP*32*32];
    const int mt = blockIdx.x, b = blockIdx.y;
    const int t = threadIdx.x, lane = t & 63, w = t >> 6;
    const int quad = lane >> 4, l16 = lane & 15;
    const int s0 = mt * 64;
    const int e0 = idx[b*2+0], e1 = idx[b*2+1];
    const float g0 = gates[b*2+0], g1 = gates[b*2+1];

    // zero-fill the output slots for this m-tile (all 128 cols, h+l, NP projs)
    {
        short8 z = {0,0,0,0,0,0,0,0};
        #pragma unroll
        for (int p = 0; p < NP; ++p) {
            ush* hh = p == 0 ? o0h : p == 1 ? o1h : o2h;
            ush* ll = p == 0 ? o0l : p == 1 ? o1l : o2l;
            for (int i = t; i < 1024; i += 256) {   // 64 rows x 16 short8
                const int row = i >> 4, c8 = i & 15;
                const int s = s0 + row;
                if (s < SQ) {
                    const size_t off = ((size_t)(b * SQ + s)) * 128 + c8 * 8;
                    *(short8*)&hh[off] = z;
                    *(short8*)&ll[off] = z;
                }
            }
        }
    }

    floatx4 S[2*NP] = {};
    const int nloads = 8 + 4 * NP;

    for (int k0 = 0; k0 < Dm; k0 += 32) {
        __syncthreads();
        for (int ld = w; ld < nloads; ld += 4) {
            if (ld < 8) {
                const int g = ld >> 1, isl = ld & 1;
                int s = s0 + g * 16 + (lane >> 2); if (s > SQ - 1) s = SQ - 1;
                const ush* src = (isl ? xl : xh) + ((size_t)(b * SQ + s)) * Dm + k0 + (lane & 3) * 8;
                ush* dst = (isl ? sAl : sAh) + g * 512;
                load16(src, dst);
            } else {
                const int q = ld - 8;
                const int g = q >> 1, isl = q & 1;   // g in [0, 2*NP)
                const int p = g >> 1, kk = g & 1;
                const int e = kk ? e1 : e0;
                const int r = lane >> 2;             // 0..15
                const ush* Vb = (isl ? Vl : Vh) + ((size_t)(pbase + p)) * Ee * Rr * Dm;
                const ush* src = Vb + ((size_t)(e * Rr + r)) * Dm + k0 + (lane & 3) * 8;
                ush* dst = (isl ? sBl : sBh) + g * 512;
                load16(src, dst);
            }
        }
        __syncthreads();
        const short8 ah = *(const short8*)&sAh[(w*16 + l16)*32 + quad*8];
        const short8 al = *(const short8*)&sAl[(w*16 + l16)*32 + quad*8];
        #pragma unroll
        for (int ni = 0; ni < 2*NP; ++ni) {
            const short8 bh = *(const short8*)&sBh[(ni*16 + l16)*32 + quad*8];
            const short8 bl = *(const short8*)&sBl[(ni*16 + l16)*32 + quad*8];
            S[ni] = __builtin_amdgcn_mfma_f32_16x16x32_bf16(ah, bh, S[ni], 0, 0, 0);
            S[ni] = __builtin_amdgcn_mfma_f32_16x16x32_bf16(ah, bl, S[ni], 0, 0, 0);
            S[ni] = __builtin_amdgcn_mfma_f32_16x16x32_bf16(al, bh, S[ni], 0, 0, 0);
        }
    }

    #pragma unroll
    for (int ni = 0; ni < 2*NP; ++ni) {
        const int p = ni >> 1, kk = ni & 1;
        const int e = kk ? e1 : e0;
        const float g = kk ? g1 : g0;
        const float* Sp = p == 0 ? S0 : p == 1 ? S1 : S2;
        const float scale = g * Sp[e * Rr + l16];
        ush* hh = p == 0 ? o0h : p == 1 ? o1h : o2h;
        ush* ll = p == 0 ? o0l : p == 1 ? o1l : o2l;
        #pragma unroll
        for (int r = 0; r < 4; ++r) {
            const int s = s0 + w * 16 + quad * 4 + r;
            if (s < SQ) {
                const float val = S[ni][r] * scale;
                const ush hv = f2bf(val);
                const size_t off = ((size_t)(b * SQ + s)) * 128 + e * 16 + l16;
                hh[off] = hv;
                ll[off] = f2bf(val - bf2f(hv));
            }
        }
    }
}

// -------------------------------- split-bf16 MFMA GEMM, K=1152 (1024+ext) ---
__global__ __launch_bounds__(256) void gemm_mfma(
    const ush* __restrict__ xh, const ush* __restrict__ xl,
    const ush* __restrict__ e0h, const ush* __restrict__ e0l,
    const ush* __restrict__ e1h, const ush* __restrict__ e1l,
    const ush* __restrict__ e2h, const ush* __restrict__ e2l,
    const ush* __restrict__ B0h, const ush* __restrict__ B0l,
    const ush* __restrict__ B1h, const ush* __restrict__ B1l,
    const ush* __restrict__ B2h, const ush* __restrict__ B2l,
    const float* __restrict__ b0, const float* __restrict__ b1, const float* __restrict__ b2,
    float* __restrict__ y0, float* __restrict__ y1, float* __restrict__ y2,
    float scale0)
{
    const int z = blockIdx.z;
    const ush* Eh = z == 0 ? e0h : z == 1 ? e1h : e2h;
    const ush* El = z == 0 ? e0l : z == 1 ? e1l : e2l;
    const ush* Bh = z == 0 ? B0h : z == 1 ? B1h : B2h;
    const ush* Bl = z == 0 ? B0l : z == 1 ? B1l : B2l;
    const float* bias = z == 0 ? b0 : z == 1 ? b1 : b2;
    float* y = z == 0 ? y0 : z == 1 ? y1 : y2;
    const float scale = z == 0 ? scale0 : 1.0f;

    __shared__ ush sAh[128*32], sAl[128*32], sBh[128*32], sBl[128*32];
    const int t = threadIdx.x, lane = t & 63, w = t >> 6;
    const int m0 = blockIdx.y * 128, n0 = blockIdx.x * 128;

    floatx4 acc[4][4] = {};

    const int srow = w * 32 + (lane >> 2);
    const int scol = (lane & 3) * 8;
    const int wm = w >> 1, wn = w & 1;
    const int arow = wm * 64 + (lane & 15);
    const int brow = wn * 64 + (lane & 15);
    const int koff = (lane >> 4) * 8;

    for (int k0 = 0; k0 < KX; k0 += 32) {
        const ush *ab, *lb; size_t astr; int acol;
        if (k0 < Dm) { ab = xh; lb = xl; astr = Dm;  acol = k0; }
        else         { ab = Eh; lb = El; astr = 128; acol = k0 - Dm; }
        __syncthreads();
        #pragma unroll
        for (int i = 0; i < 2; ++i) {
            const int row = srow + i * 16;
            int rg = m0 + row; if (rg > NT - 1) rg = NT - 1;
            load16(ab + (size_t)rg * astr + acol + scol, &sAh[w*1024 + i*512]);
            load16(lb + (size_t)rg * astr + acol + scol, &sAl[w*1024 + i*512]);
            load16(Bh + (size_t)(n0 + row) * KX + k0 + scol, &sBh[w*1024 + i*512]);
            load16(Bl + (size_t)(n0 + row) * KX + k0 + scol, &sBl[w*1024 + i*512]);
        }
        __syncthreads();
        short8 ah[4], al[4], bh[4], bl[4];
        #pragma unroll
        for (int i = 0; i < 4; ++i) {
            ah[i] = *(const short8*)&sAh[(arow + i*16)*32 + koff];
            al[i] = *(const short8*)&sAl[(arow + i*16)*32 + koff];
            bh[i] = *(const short8*)&sBh[(brow + i*16)*32 + koff];
            bl[i] = *(const short8*)&sBl[(brow + i*16)*32 + koff];
        }
        #pragma unroll
        for (int mi = 0; mi < 4; ++mi)
            #pragma unroll
            for (int ni = 0; ni < 4; ++ni) {
                acc[mi][ni] = __builtin_amdgcn_mfma_f32_16x16x32_bf16(ah[mi], bh[ni], acc[mi][ni], 0, 0, 0);
                acc[mi][ni] = __builtin_amdgcn_mfma_f32_16x16x32_bf16(ah[mi], bl[ni], acc[mi][ni], 0, 0, 0);
                acc[mi][ni] = __builtin_amdgcn_mfma_f32_16x16x32_bf16(al[mi], bh[ni], acc[mi][ni], 0, 0, 0);
            }
    }

    #pragma unroll
    for (int mi = 0; mi < 4; ++mi) {
        #pragma unroll
        for (int ni = 0; ni < 4; ++ni) {
            const int col = n0 + wn*64 + ni*16 + (lane & 15);
            const float bsv = bias[col];
            const int rbase = m0 + wm*64 + mi*16 + (lane >> 4) * 4;
            #pragma unroll
            for (int r = 0; r < 4; ++r) {
                const int row = rbase + r;
                if (row < NT) y[(size_t)row * Dm + col] = (acc[mi][ni][r] + bsv) * scale;
            }
        }
    }
}

// ------------------------------------- MFMA flash attention (bf16 splits) ---
__global__ __launch_bounds__(256) void attn_mfma(
    const float* __restrict__ q, const float* __restrict__ k,
    const float* __restrict__ v, ush* __restrict__ ch, ush* __restrict__ cl)
{
    __shared__ ush sKh[64*LDP], sKl[64*LDP], sVt[64*LDP];
    __shared__ ush sP[4][16*LDP];
    const int qt = blockIdx.x, h = blockIdx.y, b = blockIdx.z;
    const int t = threadIdx.x, lane = t & 63, w = t >> 6;
    const int quad = lane >> 4, l16 = lane & 15;
    const size_t base = (size_t)b * SQ * Dm + (size_t)h * HD;

    #pragma unroll
    for (int i = 0; i < 4; ++i) {
        const int c = t + i * 256;
        const int row = c >> 4, c4 = c & 15;
        int s = qt * 64 + row; if (s > SQ - 1) s = SQ - 1;
        float4 vq = *(const float4*)(q + base + (size_t)s * Dm + c4 * 4);
        ushort4v hv, lv;
        hv.x = f2bf(vq.x); lv.x = f2bf(vq.x - bf2f(hv.x));
        hv.y = f2bf(vq.y); lv.y = f2bf(vq.y - bf2f(hv.y));
        hv.z = f2bf(vq.z); lv.z = f2bf(vq.z - bf2f(hv.z));
        hv.w = f2bf(vq.w); lv.w = f2bf(vq.w - bf2f(hv.w));
        *(ushort4v*)&sKh[row*LDP + c4*4] = hv;
        *(ushort4v*)&sKl[row*LDP + c4*4] = lv;
    }
    __syncthreads();
    short8 qh[2], ql[2];
    #pragma unroll
    for (int s = 0; s < 2; ++s) {
        qh[s] = *(const short8*)&sKh[(w*16 + l16)*LDP + s*32 + quad*8];
        ql[s] = *(const short8*)&sKl[(w*16 + l16)*LDP + s*32 + quad*8];
    }

    floatx4 O[4] = {};
    float mrow[4], lrow[4];
    #pragma unroll
    for (int r = 0; r < 4; ++r) { mrow[r] = -1e30f; lrow[r] = 0.f; }
    const bool active = (qt * 64 + w * 16) < SQ;

    for (int kt = 0; kt < 5; ++kt) {
        __syncthreads();
        #pragma unroll
        for (int i = 0; i < 4; ++i) {
            const int c = t + i * 256;
            const int row = c >> 4, c4 = c & 15;
            const int s = kt * 64 + row;
            float4 kv4 = make_float4(0.f,0.f,0.f,0.f);
            float4 vv4 = make_float4(0.f,0.f,0.f,0.f);
            if (s < SQ) {
                kv4 = *(const float4*)(k + base + (size_t)s * Dm + c4 * 4);
                vv4 = *(const float4*)(v + base + (size_t)s * Dm + c4 * 4);
            }
            ushort4v hv, lv;
            hv.x = f2bf(kv4.x); lv.x = f2bf(kv4.x - bf2f(hv.x));
            hv.y = f2bf(kv4.y); lv.y = f2bf(kv4.y - bf2f(hv.y));
            hv.z = f2bf(kv4.z); lv.z = f2bf(kv4.z - bf2f(hv.z));
            hv.w = f2bf(kv4.w); lv.w = f2bf(kv4.w - bf2f(hv.w));
            *(ushort4v*)&sKh[row*LDP + c4*4] = hv;
            *(ushort4v*)&sKl[row*LDP + c4*4] = lv;
            sVt[(c4*4+0)*LDP + row] = f2bf(vv4.x);
            sVt[(c4*4+1)*LDP + row] = f2bf(vv4.y);
            sVt[(c4*4+2)*LDP + row] = f2bf(vv4.z);
            sVt[(c4*4+3)*LDP + row] = f2bf(vv4.w);
        }
        __syncthreads();
        if (!active) continue;

        floatx4 S[4] = {};
        #pragma unroll
        for (int ni = 0; ni < 4; ++ni)
            #pragma unroll
            for (int s = 0; s < 2; ++s) {
                short8 kh = *(const short8*)&sKh[(ni*16 + l16)*LDP + s*32 + quad*8];
                short8 kl = *(const short8*)&sKl[(ni*16 + l16)*LDP + s*32 + quad*8];
                S[ni] = __builtin_amdgcn_mfma_f32_16x16x32_bf16(qh[s], kh, S[ni], 0, 0, 0);
                S[ni] = __builtin_amdgcn_mfma_f32_16x16x32_bf16(qh[s], kl, S[ni], 0, 0, 0);
                S[ni] = __builtin_amdgcn_mfma_f32_16x16x32_bf16(ql[s], kh, S[ni], 0, 0, 0);
            }
        #pragma unroll
        for (int ni = 0; ni < 4; ++ni) {
            const int jg = kt * 64 + ni * 16 + l16;
            if (jg >= SQ) { S[ni][0] = -1e30f; S[ni][1] = -1e30f; S[ni][2] = -1e30f; S[ni][3] = -1e30f; }
        }
        float mnew[4], alpha[4];
        #pragma unroll
        for (int r = 0; r < 4; ++r) {
            float mx = fmaxf(fmaxf(S[0][r], S[1][r]), fmaxf(S[2][r], S[3][r]));
            #pragma unroll
            for (int off = 1; off < 16; off <<= 1) mx = fmaxf(mx, __shfl_xor(mx, off, 64));
            mnew[r] = fmaxf(mrow[r], mx);
            alpha[r] = __expf(mrow[r] - mnew[r]);
            mrow[r] = mnew[r];
        }
        float p[4][4], rs[4];
        #pragma unroll
        for (int r = 0; r < 4; ++r) rs[r] = 0.f;
        #pragma unroll
        for (int ni = 0; ni < 4; ++ni)
            #pragma unroll
            for (int r = 0; r < 4; ++r) {
                float e = __expf(S[ni][r] - mnew[r]);
                p[ni][r] = e; rs[r] += e;
            }
        #pragma unroll
        for (int r = 0; r < 4; ++r) {
            #pragma unroll
            for (int off = 1; off < 16; off <<= 1) rs[r] += __shfl_xor(rs[r], off, 64);
            lrow[r] = lrow[r] * alpha[r] + rs[r];
        }
        #pragma unroll
        for (int ni = 0; ni < 4; ++ni)
            #pragma unroll
            for (int r = 0; r < 4; ++r) O[ni][r] *= alpha[r];
        #pragma unroll
        for (int ni = 0; ni < 4; ++ni)
            #pragma unroll
            for (int r = 0; r < 4; ++r)
                sP[w][(quad*4 + r)*LDP + ni*16 + l16] = f2bf(p[ni][r]);
        #pragma unroll
        for (int ni = 0; ni < 4; ++ni)
            #pragma unroll
            for (int s = 0; s < 2; ++s) {
                short8 a  = *(const short8*)&sP[w][l16*LDP + s*32 + quad*8];
                short8 bb = *(const short8*)&sVt[(ni*16 + l16)*LDP + s*32 + quad*8];
                O[ni] = __builtin_amdgcn_mfma_f32_16x16x32_bf16(a, bb, O[ni], 0, 0, 0);
            }
    }

    if (active) {
        #pragma unroll
        for (int ni = 0; ni < 4; ++ni) {
            const int col = h * HD + ni * 16 + l16;
            #pragma unroll
            for (int r = 0; r < 4; ++r) {
                const int s = qt * 64 + w * 16 + quad * 4 + r;
                if (s < SQ) {
                    const float val = O[ni][r] / lrow[r];
                    const size_t m = (size_t)b * SQ + s;
                    const ush hv = f2bf(val);
                    ch[m * Dm + col] = hv;
                    cl[m * Dm + col] = f2bf(val - bf2f(hv));
                }
            }
        }
    }
}

// ------------------------------------------------------------------ launch --
extern "C" void kernel_launch(void* const* d_in, const int* in_sizes, int n_in,
                              void* d_out, int out_size, void* d_ws, size_t ws_size,
                              hipStream_t stream)
{
    const float* x   = (const float*)d_in[0];
    const float* gw1 = (const float*)d_in[1];
    const float* gb1 = (const float*)d_in[2];
    const float* gw2 = (const float*)d_in[3];
    const float* gb2 = (const float*)d_in[4];
    const float *Wm[4], *U[4], *Sv[4], *Vv[4], *bias[4];
    for (int p = 0; p < 4; ++p) {
        Wm[p]   = (const float*)d_in[5 + p*5 + 0];
        U[p]    = (const float*)d_in[5 + p*5 + 1];
        Sv[p]   = (const float*)d_in[5 + p*5 + 2];
        Vv[p]   = (const float*)d_in[5 + p*5 + 3];
        bias[p] = (const float*)d_in[5 + p*5 + 4];
    }
    char* wsb   = (char*)d_ws;
    float* gates = (float*)wsb;           // 64 floats
    int*   idx   = (int*)(wsb + 256);     // 64 ints
    float* pool  = (float*)(wsb + 1024);  // 32*16*1024 floats = 2 MB
    ush* p = (ush*)(wsb + 1024 + (size_t)Bb * 16 * Dm * 4);
    ush* xh = p; p += (size_t)NT * Dm;
    ush* xl = p; p += (size_t)NT * Dm;
    ush *eh[4], *el[4];
    for (int i = 0; i < 4; ++i) { eh[i] = p; p += (size_t)NT * 128; el[i] = p; p += (size_t)NT * 128; }
    ush *Bh[4], *Bl[4];
    for (int i = 0; i < 4; ++i) { Bh[i] = p; p += (size_t)1024 * KX; Bl[i] = p; p += (size_t)1024 * KX; }
    ush* Vh = p; p += (size_t)4 * Ee * Rr * Dm;
    ush* Vl = p; p += (size_t)4 * Ee * Rr * Dm;
    float* qb = (float*)p;
    float* kb = qb + (size_t)NT * Dm;
    float* vb = kb + (size_t)NT * Dm;

    pool_kernel<<<dim3(16, Bb), 256, 0, stream>>>(x, pool);
    gating2_kernel<<<Bb, 256, 0, stream>>>(pool, gw1, gb1, gw2, gb2, gates, idx);
    convx_kernel<<<NT, 256, 0, stream>>>(x, xh, xl);
    convV_kernel<<<dim3(128, 4), 256, 0, stream>>>(Vv[0], Vv[1], Vv[2], Vv[3], Vh, Vl);
    for (int i = 0; i < 4; ++i)
        convB_kernel<<<1152, 256, 0, stream>>>(Wm[i], U[i], Bh[i], Bl[i]);

    ext_gemm<3><<<dim3(5, Bb), 256, 0, stream>>>(xh, xl, Vh, Vl,
        Sv[0], Sv[1], Sv[2],
        eh[0], el[0], eh[1], el[1], eh[2], el[2], gates, idx, 0);

    gemm_mfma<<<dim3(8, 65, 3), 256, 0, stream>>>(
        xh, xl, eh[0], el[0], eh[1], el[1], eh[2], el[2],
        Bh[0], Bl[0], Bh[1], Bl[1], Bh[2], Bl[2],
        bias[0], bias[1], bias[2], qb, kb, vb, 0.125f);

    attn_mfma<<<dim3(5, 16, Bb), 256, 0, stream>>>(qb, kb, vb, xh, xl);

    ext_gemm<1><<<dim3(5, Bb), 256, 0, stream>>>(xh, xl, Vh, Vl,
        Sv[3], Sv[3], Sv[3],
        eh[3], el[3], eh[3], el[3], eh[3], el[3], gates, idx, 3);

    gemm_mfma<<<dim3(8, 65, 1), 256, 0, stream>>>(
        xh, xl, eh[3], el[3], eh[3], el[3], eh[3], el[3],
        Bh[3], Bl[3], Bh[3], Bl[3], Bh[3], Bl[3],
        bias[3], bias[3], bias[3], (float*)d_out, (float*)d_out, (float*)d_out, 1.0f);
}

// Round 5
// 654.752 us; speedup vs baseline: 4.9353x; 1.0601x over previous
//
#include <hip/hip_runtime.h>
#include <math.h>

#define Bb   32
#define SQ   257
#define Dm   1024
#define HD   64
#define Ee   8
#define Rr   16
#define GHh  256
#define NT   (Bb*SQ)   // 8224
#define KX   1152      // 1024 + E*R extension
#define LDP  72        // padded LDS row (64 ush + 8) — attn only

typedef unsigned short ush;
typedef __attribute__((ext_vector_type(8))) short short8;
typedef __attribute__((ext_vector_type(4))) float floatx4;
typedef __attribute__((ext_vector_type(4))) unsigned short ushort4v;

__device__ __forceinline__ ush f2bf(float f) {
    union { float f; unsigned u; } a; a.f = f;
    unsigned r = a.u + 0x7fff + ((a.u >> 16) & 1);   // RNE
    return (ush)(r >> 16);
}
__device__ __forceinline__ float bf2f(ush u) {
    union { unsigned u; float f; } a; a.u = ((unsigned)u) << 16; return a.f;
}
__device__ __forceinline__ void load16(const ush* g, ush* l) {
    __builtin_amdgcn_global_load_lds(
        (const __attribute__((address_space(1))) unsigned int*)g,
        (__attribute__((address_space(3))) unsigned int*)l,
        16, 0, 0);
}

// ----------------------------------------------------- gating stage A: pool -
__global__ __launch_bounds__(256) void pool_kernel(
    const float* __restrict__ x, float* __restrict__ pp)
{
    const int c = blockIdx.x, b = blockIdx.y, t = threadIdx.x;
    const int s0 = c * 16, s1 = (c == 15) ? SQ : s0 + 16;
    float4 acc = make_float4(0.f, 0.f, 0.f, 0.f);
    const float* xp = x + ((size_t)b * SQ + s0) * Dm + t * 4;
    for (int s = s0; s < s1; ++s, xp += Dm) {
        float4 v = *(const float4*)xp;
        acc.x += v.x; acc.y += v.y; acc.z += v.z; acc.w += v.w;
    }
    *(float4*)(pp + ((size_t)b * 16 + c) * Dm + t * 4) = acc;
}

// ----------------------------------------------- gating stage B: MLP + top2 -
__global__ __launch_bounds__(256) void gating2_kernel(
    const float* __restrict__ pp, const float* __restrict__ gw1,
    const float* __restrict__ gb1, const float* __restrict__ gw2,
    const float* __restrict__ gb2,
    float* __restrict__ gates, int* __restrict__ idx)
{
    __shared__ float pooled[Dm];
    __shared__ float hbuf[GHh];
    __shared__ float logits[Ee];
    const int b = blockIdx.x, t = threadIdx.x;
    const int w = t >> 6, lane = t & 63;

    float4 acc = make_float4(0.f, 0.f, 0.f, 0.f);
    for (int c = 0; c < 16; ++c) {
        float4 v = *(const float4*)(pp + ((size_t)b * 16 + c) * Dm + t * 4);
        acc.x += v.x; acc.y += v.y; acc.z += v.z; acc.w += v.w;
    }
    const float sc = 1.0f / SQ;
    pooled[t*4+0] = acc.x * sc; pooled[t*4+1] = acc.y * sc;
    pooled[t*4+2] = acc.z * sc; pooled[t*4+3] = acc.w * sc;
    __syncthreads();

    for (int oi = 0; oi < 64; ++oi) {
        const int o = w * 64 + oi;
        const float* g = gw1 + (size_t)o * Dm;
        float s = 0.f;
        #pragma unroll
        for (int i = 0; i < 16; ++i) s += pooled[lane + i*64] * g[lane + i*64];
        for (int off = 32; off > 0; off >>= 1) s += __shfl_down(s, off, 64);
        if (lane == 0) hbuf[o] = fmaxf(s + gb1[o], 0.f);
    }
    __syncthreads();
    if (t < Ee) {
        const float* g = gw2 + t * GHh;
        float s = 0.f;
        for (int j = 0; j < GHh; ++j) s += hbuf[j] * g[j];
        logits[t] = s + gb2[t];
    }
    __syncthreads();
    if (t == 0) {
        int i1 = 0; float v1 = logits[0];
        for (int e = 1; e < Ee; ++e) if (logits[e] > v1) { v1 = logits[e]; i1 = e; }
        int i2 = 0; float v2 = -1e30f;
        for (int e = 0; e < Ee; ++e) if (e != i1 && logits[e] > v2) { v2 = logits[e]; i2 = e; }
        float e2 = __expf(v2 - v1);
        float inv = 1.f / (1.f + e2);
        gates[b*2+0] = inv; gates[b*2+1] = e2 * inv;
        idx[b*2+0] = i1; idx[b*2+1] = i2;
    }
}

// ------------------------------------------------ fp32 -> split bf16 (rows) -
__global__ __launch_bounds__(256) void convx_kernel(
    const float* __restrict__ x, ush* __restrict__ xh, ush* __restrict__ xl)
{
    const int m = blockIdx.x, t = threadIdx.x;
    float4 v = *(const float4*)(x + (size_t)m * Dm + t * 4);
    ushort4v hv, lv;
    hv.x = f2bf(v.x); lv.x = f2bf(v.x - bf2f(hv.x));
    hv.y = f2bf(v.y); lv.y = f2bf(v.y - bf2f(hv.y));
    hv.z = f2bf(v.z); lv.z = f2bf(v.z - bf2f(hv.z));
    hv.w = f2bf(v.w); lv.w = f2bf(v.w - bf2f(hv.w));
    *(ushort4v*)(xh + (size_t)m * Dm + t * 4) = hv;
    *(ushort4v*)(xl + (size_t)m * Dm + t * 4) = lv;
}

// --------------------------------- W,U -> split bf16 B matrix (1024 x 1152) -
__global__ __launch_bounds__(256) void convB_kernel(
    const float* __restrict__ W0, const float* __restrict__ U0,
    const float* __restrict__ W1, const float* __restrict__ U1,
    const float* __restrict__ W2, const float* __restrict__ U2,
    const float* __restrict__ W3, const float* __restrict__ U3,
    ush* __restrict__ Bh0, ush* __restrict__ Bl0,
    ush* __restrict__ Bh1, ush* __restrict__ Bl1,
    ush* __restrict__ Bh2, ush* __restrict__ Bl2,
    ush* __restrict__ Bh3, ush* __restrict__ Bl3)
{
    const int p = blockIdx.y;
    const float* W = p == 0 ? W0 : p == 1 ? W1 : p == 2 ? W2 : W3;
    const float* U = p == 0 ? U0 : p == 1 ? U1 : p == 2 ? U2 : U3;
    ush* Bh = p == 0 ? Bh0 : p == 1 ? Bh1 : p == 2 ? Bh2 : Bh3;
    ush* Bl = p == 0 ? Bl0 : p == 1 ? Bl1 : p == 2 ? Bl2 : Bl3;
    const int i = blockIdx.x * 256 + threadIdx.x;
    const int n = i / 288, c4 = i % 288, col = c4 * 4;
    float4 v;
    if (col < Dm) {
        v = *(const float4*)(W + (size_t)n * Dm + col);
    } else {
        int ec = col - Dm, e = ec >> 4, r = ec & 15;
        v = *(const float4*)(U + ((size_t)(e * Dm + n)) * Rr + r);
    }
    ushort4v hv, lv;
    hv.x = f2bf(v.x); lv.x = f2bf(v.x - bf2f(hv.x));
    hv.y = f2bf(v.y); lv.y = f2bf(v.y - bf2f(hv.y));
    hv.z = f2bf(v.z); lv.z = f2bf(v.z - bf2f(hv.z));
    hv.w = f2bf(v.w); lv.w = f2bf(v.w - bf2f(hv.w));
    *(ushort4v*)(Bh + (size_t)n * KX + col) = hv;
    *(ushort4v*)(Bl + (size_t)n * KX + col) = lv;
}

// ------------------------------------------------- V -> split bf16 (4 proj) -
__global__ __launch_bounds__(256) void convV_kernel(
    const float* __restrict__ V0, const float* __restrict__ V1,
    const float* __restrict__ V2, const float* __restrict__ V3,
    ush* __restrict__ Vh, ush* __restrict__ Vl)
{
    const int p = blockIdx.y;
    const float* V = p == 0 ? V0 : p == 1 ? V1 : p == 2 ? V2 : V3;
    const size_t i = ((size_t)blockIdx.x * 256 + threadIdx.x) * 4;
    float4 v = *(const float4*)(V + i);
    ushort4v hv, lv;
    hv.x = f2bf(v.x); lv.x = f2bf(v.x - bf2f(hv.x));
    hv.y = f2bf(v.y); lv.y = f2bf(v.y - bf2f(hv.y));
    hv.z = f2bf(v.z); lv.z = f2bf(v.z - bf2f(hv.z));
    hv.w = f2bf(v.w); lv.w = f2bf(v.w - bf2f(hv.w));
    const size_t off = (size_t)p * Ee * Rr * Dm + i;
    *(ushort4v*)(Vh + off) = hv;
    *(ushort4v*)(Vl + off) = lv;
}

// --------------- ext as MFMA GEMM: xvs[s,j] = gS * (x[s,:] . Vsel[j,:]) -----
// XOR-swizzled LDS chunks: slot c' holds global chunk c'^((row>>1)&3).
template<int NP>
__global__ __launch_bounds__(256) void ext_gemm(
    const ush* __restrict__ xh, const ush* __restrict__ xl,
    const ush* __restrict__ Vh, const ush* __restrict__ Vl,   // [4][128][1024]
    const float* __restrict__ S0, const float* __restrict__ S1,
    const float* __restrict__ S2,
    ush* __restrict__ o0h, ush* __restrict__ o0l,
    ush* __restrict__ o1h, ush* __restrict__ o1l,
    ush* __restrict__ o2h, ush* __restrict__ o2l,
    const float* __restrict__ gates, const int* __restrict__ idx, int pbase)
{
    __shared__ ush sAh[64*32], sAl[64*32], sBh[NP*32*32], sBl[NP*32*32];
    const int mt = blockIdx.x, b = blockIdx.y;
    const int t = threadIdx.x, lane = t & 63, w = t >> 6;
    const int quad = lane >> 4, l16 = lane & 15;
    const int s0 = mt * 64;
    const int e0 = idx[b*2+0], e1 = idx[b*2+1];
    const float g0 = gates[b*2+0], g1 = gates[b*2+1];
    const int swsrc = ((lane & 3) ^ ((lane >> 3) & 3)) * 8;  // staging source chunk
    const int swrd  = ((quad ^ ((l16 >> 1) & 3)) * 8);       // read chunk

    {
        short8 z = {0,0,0,0,0,0,0,0};
        #pragma unroll
        for (int p = 0; p < NP; ++p) {
            ush* hh = p == 0 ? o0h : p == 1 ? o1h : o2h;
            ush* ll = p == 0 ? o0l : p == 1 ? o1l : o2l;
            for (int i = t; i < 1024; i += 256) {
                const int row = i >> 4, c8 = i & 15;
                const int s = s0 + row;
                if (s < SQ) {
                    const size_t off = ((size_t)(b * SQ + s)) * 128 + c8 * 8;
                    *(short8*)&hh[off] = z;
                    *(short8*)&ll[off] = z;
                }
            }
        }
    }

    floatx4 S[2*NP] = {};
    const int nloads = 8 + 4 * NP;

    for (int k0 = 0; k0 < Dm; k0 += 32) {
        __syncthreads();
        for (int ld = w; ld < nloads; ld += 4) {
            if (ld < 8) {
                const int g = ld >> 1, isl = ld & 1;
                int s = s0 + g * 16 + (lane >> 2); if (s > SQ - 1) s = SQ - 1;
                const ush* src = (isl ? xl : xh) + ((size_t)(b * SQ + s)) * Dm + k0 + swsrc;
                ush* dst = (isl ? sAl : sAh) + g * 512;
                load16(src, dst);
            } else {
                const int q = ld - 8;
                const int g = q >> 1, isl = q & 1;
                const int p = g >> 1, kk = g & 1;
                const int e = kk ? e1 : e0;
                const int r = lane >> 2;
                const ush* Vb = (isl ? Vl : Vh) + ((size_t)(pbase + p)) * Ee * Rr * Dm;
                const ush* src = Vb + ((size_t)(e * Rr + r)) * Dm + k0 + swsrc;
                ush* dst = (isl ? sBl : sBh) + g * 512;
                load16(src, dst);
            }
        }
        __syncthreads();
        const short8 ah = *(const short8*)&sAh[(w*16 + l16)*32 + swrd];
        const short8 al = *(const short8*)&sAl[(w*16 + l16)*32 + swrd];
        #pragma unroll
        for (int ni = 0; ni < 2*NP; ++ni) {
            const short8 bh = *(const short8*)&sBh[(ni*16 + l16)*32 + swrd];
            const short8 bl = *(const short8*)&sBl[(ni*16 + l16)*32 + swrd];
            S[ni] = __builtin_amdgcn_mfma_f32_16x16x32_bf16(ah, bh, S[ni], 0, 0, 0);
            S[ni] = __builtin_amdgcn_mfma_f32_16x16x32_bf16(ah, bl, S[ni], 0, 0, 0);
            S[ni] = __builtin_amdgcn_mfma_f32_16x16x32_bf16(al, bh, S[ni], 0, 0, 0);
        }
    }

    #pragma unroll
    for (int ni = 0; ni < 2*NP; ++ni) {
        const int p = ni >> 1, kk = ni & 1;
        const int e = kk ? e1 : e0;
        const float g = kk ? g1 : g0;
        const float* Sp = p == 0 ? S0 : p == 1 ? S1 : S2;
        const float scale = g * Sp[e * Rr + l16];
        ush* hh = p == 0 ? o0h : p == 1 ? o1h : o2h;
        ush* ll = p == 0 ? o0l : p == 1 ? o1l : o2l;
        #pragma unroll
        for (int r = 0; r < 4; ++r) {
            const int s = s0 + w * 16 + quad * 4 + r;
            if (s < SQ) {
                const float val = S[ni][r] * scale;
                const ush hv = f2bf(val);
                const size_t off = ((size_t)(b * SQ + s)) * 128 + e * 16 + l16;
                hh[off] = hv;
                ll[off] = f2bf(val - bf2f(hv));
            }
        }
    }
}

// -------------------------------- split-bf16 MFMA GEMM, K=1152 (1024+ext) ---
// grid.x = 72*8 (n = x/72, m-stripe = x%72, dead if >=65) so the 8 n-tiles of
// one m-stripe share an XCD (round-robin dispatch) -> A-stripe L2 reuse.
__global__ __launch_bounds__(256) void gemm_mfma(
    const ush* __restrict__ xh, const ush* __restrict__ xl,
    const ush* __restrict__ e0h, const ush* __restrict__ e0l,
    const ush* __restrict__ e1h, const ush* __restrict__ e1l,
    const ush* __restrict__ e2h, const ush* __restrict__ e2l,
    const ush* __restrict__ B0h, const ush* __restrict__ B0l,
    const ush* __restrict__ B1h, const ush* __restrict__ B1l,
    const ush* __restrict__ B2h, const ush* __restrict__ B2l,
    const float* __restrict__ b0, const float* __restrict__ b1, const float* __restrict__ b2,
    float* __restrict__ y0, float* __restrict__ y1, float* __restrict__ y2,
    float scale0)
{
    const int stripe = blockIdx.x % 72;
    if (stripe >= 65) return;
    const int nb = blockIdx.x / 72;
    const int z = blockIdx.z;
    const ush* Eh = z == 0 ? e0h : z == 1 ? e1h : e2h;
    const ush* El = z == 0 ? e0l : z == 1 ? e1l : e2l;
    const ush* Bh = z == 0 ? B0h : z == 1 ? B1h : B2h;
    const ush* Bl = z == 0 ? B0l : z == 1 ? B1l : B2l;
    const float* bias = z == 0 ? b0 : z == 1 ? b1 : b2;
    float* y = z == 0 ? y0 : z == 1 ? y1 : y2;
    const float scale = z == 0 ? scale0 : 1.0f;

    __shared__ ush sAh[128*32], sAl[128*32], sBh[128*32], sBl[128*32];
    const int t = threadIdx.x, lane = t & 63, w = t >> 6;
    const int m0 = stripe * 128, n0 = nb * 128;

    floatx4 acc[4][4] = {};

    const int srow = w * 32 + (lane >> 2);
    const int swsrc = ((lane & 3) ^ ((lane >> 3) & 3)) * 8;  // swizzled source chunk
    const int wm = w >> 1, wn = w & 1;
    const int l16 = lane & 15, quad = lane >> 4;
    const int arow = wm * 64 + l16;
    const int brow = wn * 64 + l16;
    const int swrd = (quad ^ ((l16 >> 1) & 3)) * 8;          // swizzled read chunk

    for (int k0 = 0; k0 < KX; k0 += 32) {
        const ush *ab, *lb; size_t astr; int acol;
        if (k0 < Dm) { ab = xh; lb = xl; astr = Dm;  acol = k0; }
        else         { ab = Eh; lb = El; astr = 128; acol = k0 - Dm; }
        __syncthreads();
        #pragma unroll
        for (int i = 0; i < 2; ++i) {
            const int row = srow + i * 16;
            int rg = m0 + row; if (rg > NT - 1) rg = NT - 1;
            load16(ab + (size_t)rg * astr + acol + swsrc, &sAh[w*1024 + i*512]);
            load16(lb + (size_t)rg * astr + acol + swsrc, &sAl[w*1024 + i*512]);
            load16(Bh + (size_t)(n0 + row) * KX + k0 + swsrc, &sBh[w*1024 + i*512]);
            load16(Bl + (size_t)(n0 + row) * KX + k0 + swsrc, &sBl[w*1024 + i*512]);
        }
        __syncthreads();
        short8 ah[4], al[4], bh[4], bl[4];
        #pragma unroll
        for (int i = 0; i < 4; ++i) {
            ah[i] = *(const short8*)&sAh[(arow + i*16)*32 + swrd];
            al[i] = *(const short8*)&sAl[(arow + i*16)*32 + swrd];
            bh[i] = *(const short8*)&sBh[(brow + i*16)*32 + swrd];
            bl[i] = *(const short8*)&sBl[(brow + i*16)*32 + swrd];
        }
        #pragma unroll
        for (int mi = 0; mi < 4; ++mi)
            #pragma unroll
            for (int ni = 0; ni < 4; ++ni) {
                acc[mi][ni] = __builtin_amdgcn_mfma_f32_16x16x32_bf16(ah[mi], bh[ni], acc[mi][ni], 0, 0, 0);
                acc[mi][ni] = __builtin_amdgcn_mfma_f32_16x16x32_bf16(ah[mi], bl[ni], acc[mi][ni], 0, 0, 0);
                acc[mi][ni] = __builtin_amdgcn_mfma_f32_16x16x32_bf16(al[mi], bh[ni], acc[mi][ni], 0, 0, 0);
            }
    }

    #pragma unroll
    for (int mi = 0; mi < 4; ++mi) {
        #pragma unroll
        for (int ni = 0; ni < 4; ++ni) {
            const int col = n0 + wn*64 + ni*16 + l16;
            const float bsv = bias[col];
            const int rbase = m0 + wm*64 + mi*16 + quad * 4;
            #pragma unroll
            for (int r = 0; r < 4; ++r) {
                const int row = rbase + r;
                if (row < NT) y[(size_t)row * Dm + col] = (acc[mi][ni][r] + bsv) * scale;
            }
        }
    }
}

// ------------------------------------- MFMA flash attention (bf16 splits) ---
__global__ __launch_bounds__(256) void attn_mfma(
    const float* __restrict__ q, const float* __restrict__ k,
    const float* __restrict__ v, ush* __restrict__ ch, ush* __restrict__ cl)
{
    __shared__ ush sKh[64*LDP], sKl[64*LDP], sVt[64*LDP];
    __shared__ ush sP[4][16*LDP];
    const int qt = blockIdx.x, h = blockIdx.y, b = blockIdx.z;
    const int t = threadIdx.x, lane = t & 63, w = t >> 6;
    const int quad = lane >> 4, l16 = lane & 15;
    const size_t base = (size_t)b * SQ * Dm + (size_t)h * HD;

    #pragma unroll
    for (int i = 0; i < 4; ++i) {
        const int c = t + i * 256;
        const int row = c >> 4, c4 = c & 15;
        int s = qt * 64 + row; if (s > SQ - 1) s = SQ - 1;
        float4 vq = *(const float4*)(q + base + (size_t)s * Dm + c4 * 4);
        ushort4v hv, lv;
        hv.x = f2bf(vq.x); lv.x = f2bf(vq.x - bf2f(hv.x));
        hv.y = f2bf(vq.y); lv.y = f2bf(vq.y - bf2f(hv.y));
        hv.z = f2bf(vq.z); lv.z = f2bf(vq.z - bf2f(hv.z));
        hv.w = f2bf(vq.w); lv.w = f2bf(vq.w - bf2f(hv.w));
        *(ushort4v*)&sKh[row*LDP + c4*4] = hv;
        *(ushort4v*)&sKl[row*LDP + c4*4] = lv;
    }
    __syncthreads();
    short8 qh[2], ql[2];
    #pragma unroll
    for (int s = 0; s < 2; ++s) {
        qh[s] = *(const short8*)&sKh[(w*16 + l16)*LDP + s*32 + quad*8];
        ql[s] = *(const short8*)&sKl[(w*16 + l16)*LDP + s*32 + quad*8];
    }

    floatx4 O[4] = {};
    float mrow[4], lrow[4];
    #pragma unroll
    for (int r = 0; r < 4; ++r) { mrow[r] = -1e30f; lrow[r] = 0.f; }
    const bool active = (qt * 64 + w * 16) < SQ;

    for (int kt = 0; kt < 5; ++kt) {
        __syncthreads();
        #pragma unroll
        for (int i = 0; i < 4; ++i) {
            const int c = t + i * 256;
            const int row = c >> 4, c4 = c & 15;
            const int s = kt * 64 + row;
            float4 kv4 = make_float4(0.f,0.f,0.f,0.f);
            float4 vv4 = make_float4(0.f,0.f,0.f,0.f);
            if (s < SQ) {
                kv4 = *(const float4*)(k + base + (size_t)s * Dm + c4 * 4);
                vv4 = *(const float4*)(v + base + (size_t)s * Dm + c4 * 4);
            }
            ushort4v hv, lv;
            hv.x = f2bf(kv4.x); lv.x = f2bf(kv4.x - bf2f(hv.x));
            hv.y = f2bf(kv4.y); lv.y = f2bf(kv4.y - bf2f(hv.y));
            hv.z = f2bf(kv4.z); lv.z = f2bf(kv4.z - bf2f(hv.z));
            hv.w = f2bf(kv4.w); lv.w = f2bf(kv4.w - bf2f(hv.w));
            *(ushort4v*)&sKh[row*LDP + c4*4] = hv;
            *(ushort4v*)&sKl[row*LDP + c4*4] = lv;
            sVt[(c4*4+0)*LDP + row] = f2bf(vv4.x);
            sVt[(c4*4+1)*LDP + row] = f2bf(vv4.y);
            sVt[(c4*4+2)*LDP + row] = f2bf(vv4.z);
            sVt[(c4*4+3)*LDP + row] = f2bf(vv4.w);
        }
        __syncthreads();
        if (!active) continue;

        floatx4 S[4] = {};
        #pragma unroll
        for (int ni = 0; ni < 4; ++ni)
            #pragma unroll
            for (int s = 0; s < 2; ++s) {
                short8 kh = *(const short8*)&sKh[(ni*16 + l16)*LDP + s*32 + quad*8];
                short8 kl = *(const short8*)&sKl[(ni*16 + l16)*LDP + s*32 + quad*8];
                S[ni] = __builtin_amdgcn_mfma_f32_16x16x32_bf16(qh[s], kh, S[ni], 0, 0, 0);
                S[ni] = __builtin_amdgcn_mfma_f32_16x16x32_bf16(qh[s], kl, S[ni], 0, 0, 0);
                S[ni] = __builtin_amdgcn_mfma_f32_16x16x32_bf16(ql[s], kh, S[ni], 0, 0, 0);
            }
        #pragma unroll
        for (int ni = 0; ni < 4; ++ni) {
            const int jg = kt * 64 + ni * 16 + l16;
            if (jg >= SQ) { S[ni][0] = -1e30f; S[ni][1] = -1e30f; S[ni][2] = -1e30f; S[ni][3] = -1e30f; }
        }
        float mnew[4], alpha[4];
        #pragma unroll
        for (int r = 0; r < 4; ++r) {
            float mx = fmaxf(fmaxf(S[0][r], S[1][r]), fmaxf(S[2][r], S[3][r]));
            #pragma unroll
            for (int off = 1; off < 16; off <<= 1) mx = fmaxf(mx, __shfl_xor(mx, off, 64));
            mnew[r] = fmaxf(mrow[r], mx);
            alpha[r] = __expf(mrow[r] - mnew[r]);
            mrow[r] = mnew[r];
        }
        float p[4][4], rs[4];
        #pragma unroll
        for (int r = 0; r < 4; ++r) rs[r] = 0.f;
        #pragma unroll
        for (int ni = 0; ni < 4; ++ni)
            #pragma unroll
            for (int r = 0; r < 4; ++r) {
                float e = __expf(S[ni][r] - mnew[r]);
                p[ni][r] = e; rs[r] += e;
            }
        #pragma unroll
        for (int r = 0; r < 4; ++r) {
            #pragma unroll
            for (int off = 1; off < 16; off <<= 1) rs[r] += __shfl_xor(rs[r], off, 64);
            lrow[r] = lrow[r] * alpha[r] + rs[r];
        }
        #pragma unroll
        for (int ni = 0; ni < 4; ++ni)
            #pragma unroll
            for (int r = 0; r < 4; ++r) O[ni][r] *= alpha[r];
        #pragma unroll
        for (int ni = 0; ni < 4; ++ni)
            #pragma unroll
            for (int r = 0; r < 4; ++r)
                sP[w][(quad*4 + r)*LDP + ni*16 + l16] = f2bf(p[ni][r]);
        #pragma unroll
        for (int ni = 0; ni < 4; ++ni)
            #pragma unroll
            for (int s = 0; s < 2; ++s) {
                short8 a  = *(const short8*)&sP[w][l16*LDP + s*32 + quad*8];
                short8 bb = *(const short8*)&sVt[(ni*16 + l16)*LDP + s*32 + quad*8];
                O[ni] = __builtin_amdgcn_mfma_f32_16x16x32_bf16(a, bb, O[ni], 0, 0, 0);
            }
    }

    if (active) {
        #pragma unroll
        for (int ni = 0; ni < 4; ++ni) {
            const int col = h * HD + ni * 16 + l16;
            #pragma unroll
            for (int r = 0; r < 4; ++r) {
                const int s = qt * 64 + w * 16 + quad * 4 + r;
                if (s < SQ) {
                    const float val = O[ni][r] / lrow[r];
                    const size_t m = (size_t)b * SQ + s;
                    const ush hv = f2bf(val);
                    ch[m * Dm + col] = hv;
                    cl[m * Dm + col] = f2bf(val - bf2f(hv));
                }
            }
        }
    }
}

// ------------------------------------------------------------------ launch --
extern "C" void kernel_launch(void* const* d_in, const int* in_sizes, int n_in,
                              void* d_out, int out_size, void* d_ws, size_t ws_size,
                              hipStream_t stream)
{
    const float* x   = (const float*)d_in[0];
    const float* gw1 = (const float*)d_in[1];
    const float* gb1 = (const float*)d_in[2];
    const float* gw2 = (const float*)d_in[3];
    const float* gb2 = (const float*)d_in[4];
    const float *Wm[4], *U[4], *Sv[4], *Vv[4], *bias[4];
    for (int p = 0; p < 4; ++p) {
        Wm[p]   = (const float*)d_in[5 + p*5 + 0];
        U[p]    = (const float*)d_in[5 + p*5 + 1];
        Sv[p]   = (const float*)d_in[5 + p*5 + 2];
        Vv[p]   = (const float*)d_in[5 + p*5 + 3];
        bias[p] = (const float*)d_in[5 + p*5 + 4];
    }
    char* wsb   = (char*)d_ws;
    float* gates = (float*)wsb;           // 64 floats
    int*   idx   = (int*)(wsb + 256);     // 64 ints
    float* pool  = (float*)(wsb + 1024);  // 32*16*1024 floats = 2 MB
    ush* p = (ush*)(wsb + 1024 + (size_t)Bb * 16 * Dm * 4);
    ush* xh = p; p += (size_t)NT * Dm;
    ush* xl = p; p += (size_t)NT * Dm;
    ush *eh[4], *el[4];
    for (int i = 0; i < 4; ++i) { eh[i] = p; p += (size_t)NT * 128; el[i] = p; p += (size_t)NT * 128; }
    ush *Bh[4], *Bl[4];
    for (int i = 0; i < 4; ++i) { Bh[i] = p; p += (size_t)1024 * KX; Bl[i] = p; p += (size_t)1024 * KX; }
    ush* Vh = p; p += (size_t)4 * Ee * Rr * Dm;
    ush* Vl = p; p += (size_t)4 * Ee * Rr * Dm;
    float* qb = (float*)p;
    float* kb = qb + (size_t)NT * Dm;
    float* vb = kb + (size_t)NT * Dm;

    pool_kernel<<<dim3(16, Bb), 256, 0, stream>>>(x, pool);
    gating2_kernel<<<Bb, 256, 0, stream>>>(pool, gw1, gb1, gw2, gb2, gates, idx);
    convx_kernel<<<NT, 256, 0, stream>>>(x, xh, xl);
    convV_kernel<<<dim3(128, 4), 256, 0, stream>>>(Vv[0], Vv[1], Vv[2], Vv[3], Vh, Vl);
    convB_kernel<<<dim3(1152, 4), 256, 0, stream>>>(
        Wm[0], U[0], Wm[1], U[1], Wm[2], U[2], Wm[3], U[3],
        Bh[0], Bl[0], Bh[1], Bl[1], Bh[2], Bl[2], Bh[3], Bl[3]);

    ext_gemm<3><<<dim3(5, Bb), 256, 0, stream>>>(xh, xl, Vh, Vl,
        Sv[0], Sv[1], Sv[2],
        eh[0], el[0], eh[1], el[1], eh[2], el[2], gates, idx, 0);

    gemm_mfma<<<dim3(576, 1, 3), 256, 0, stream>>>(
        xh, xl, eh[0], el[0], eh[1], el[1], eh[2], el[2],
        Bh[0], Bl[0], Bh[1], Bl[1], Bh[2], Bl[2],
        bias[0], bias[1], bias[2], qb, kb, vb, 0.125f);

    attn_mfma<<<dim3(5, 16, Bb), 256, 0, stream>>>(qb, kb, vb, xh, xl);

    ext_gemm<1><<<dim3(5, Bb), 256, 0, stream>>>(xh, xl, Vh, Vl,
        Sv[3], Sv[3], Sv[3],
        eh[3], el[3], eh[3], el[3], eh[3], el[3], gates, idx, 3);

    gemm_mfma<<<dim3(576, 1, 1), 256, 0, stream>>>(
        xh, xl, eh[3], el[3], eh[3], el[3], eh[3], el[3],
        Bh[3], Bl[3], Bh[3], Bl[3], Bh[3], Bl[3],
        bias[3], bias[3], bias[3], (float*)d_out, (float*)d_out, (float*)d_out, 1.0f);
}

// Round 6
// 471.823 us; speedup vs baseline: 6.8488x; 1.3877x over previous
//
#include <hip/hip_runtime.h>
#include <math.h>

#define Bb   32
#define SQ   257
#define Dm   1024
#define HD   64
#define Ee   8
#define Rr   16
#define GHh  256
#define NT   (Bb*SQ)   // 8224
#define KX   1152      // 1024 + E*R extension
#define LDP  72        // padded LDS row (64 ush + 8) — attn only

typedef unsigned short ush;
typedef _Float16 h16;
typedef __attribute__((ext_vector_type(8))) _Float16 half8;
typedef __attribute__((ext_vector_type(4))) _Float16 half4;
typedef __attribute__((ext_vector_type(8))) short short8;
typedef __attribute__((ext_vector_type(4))) float floatx4;

__device__ __forceinline__ ush f2h(float f) {
    union { h16 h; ush u; } a; a.h = (h16)f; return a.u;
}
__device__ __forceinline__ void store_h4(ush* p, float4 v) {
    half4 h; h.x = (h16)v.x; h.y = (h16)v.y; h.z = (h16)v.z; h.w = (h16)v.w;
    *(half4*)p = h;
}
__device__ __forceinline__ void load16(const ush* g, ush* l) {
    __builtin_amdgcn_global_lo\
ad_lds(
        (const __attribute__((address_space(1))) unsigned int*)g,
        (__attribute__((address_space(3))) unsigned int*)l,
        16, 0, 0);
}

// ----------------------------------------------------- gating stage A: pool -
__global__ __launch_bounds__(256) void pool_kernel(
    const float* __restrict__ x, float* __restrict__ pp)
{
    const int c = blockIdx.x, b = blockIdx.y, t = threadIdx.x;
    const int s0 = c * 16, s1 = (c == 15) ? SQ : s0 + 16;
    float4 acc = make_float4(0.f, 0.f, 0.f, 0.f);
    const float* xp = x + ((size_t)b * SQ + s0) * Dm + t * 4;
    for (int s = s0; s < s1; ++s, xp += Dm) {
        float4 v = *(const float4*)xp;
        acc.x += v.x; acc.y += v.y; acc.z += v.z; acc.w += v.w;
    }
    *(float4*)(pp + ((size_t)b * 16 + c) * Dm + t * 4) = acc;
}

// ----------------------------------------------- gating stage B: MLP + top2 -
__global__ __launch_bounds__(256) void gating2_kernel(
    const float* __restrict__ pp, const float* __restrict__ gw1,
    const float* __restrict__ gb1, const float* __restrict__ gw2,
    const float* __restrict__ gb2,
    float* __restrict__ gates, int* __restrict__ idx)
{
    __shared__ float pooled[Dm];
    __shared__ float hbuf[GHh];
    __shared__ float logits[Ee];
    const int b = blockIdx.x, t = threadIdx.x;
    const int w = t >> 6, lane = t & 63;

    float4 acc = make_float4(0.f, 0.f, 0.f, 0.f);
    for (int c = 0; c < 16; ++c) {
        float4 v = *(const float4*)(pp + ((size_t)b * 16 + c) * Dm + t * 4);
        acc.x += v.x; acc.y += v.y; acc.z += v.z; acc.w += v.w;
    }
    const float sc = 1.0f / SQ;
    pooled[t*4+0] = acc.x * sc; pooled[t*4+1] = acc.y * sc;
    pooled[t*4+2] = acc.z * sc; pooled[t*4+3] = acc.w * sc;
    __syncthreads();

    for (int oi = 0; oi < 64; ++oi) {
        const int o = w * 64 + oi;
        const float* g = gw1 + (size_t)o * Dm;
        float s = 0.f;
        #pragma unroll
        for (int i = 0; i < 16; ++i) s += pooled[lane + i*64] * g[lane + i*64];
        for (int off = 32; off > 0; off >>= 1) s += __shfl_down(s, off, 64);
        if (lane == 0) hbuf[o] = fmaxf(s + gb1[o], 0.f);
    }
    __syncthreads();
    if (t < Ee) {
        const float* g = gw2 + t * GHh;
        float s = 0.f;
        for (int j = 0; j < GHh; ++j) s += hbuf[j] * g[j];
        logits[t] = s + gb2[t];
    }
    __syncthreads();
    if (t == 0) {
        int i1 = 0; float v1 = logits[0];
        for (int e = 1; e < Ee; ++e) if (logits[e] > v1) { v1 = logits[e]; i1 = e; }
        int i2 = 0; float v2 = -1e30f;
        for (int e = 0; e < Ee; ++e) if (e != i1 && logits[e] > v2) { v2 = logits[e]; i2 = e; }
        float e2 = __expf(v2 - v1);
        float inv = 1.f / (1.f + e2);
        gates[b*2+0] = inv; gates[b*2+1] = e2 * inv;
        idx[b*2+0] = i1; idx[b*2+1] = i2;
    }
}

// ------------------------------------------------------- fp32 -> f16 (rows) -
__global__ __launch_bounds__(256) void convx_kernel(
    const float* __restrict__ x, ush* __restrict__ xf)
{
    const int m = blockIdx.x, t = threadIdx.x;
    float4 v = *(const float4*)(x + (size_t)m * Dm + t * 4);
    store_h4(xf + (size_t)m * Dm + t * 4, v);
}

// -------------------------------------- W,U -> f16 B matrix (1024 x 1152) ---
__global__ __launch_bounds__(256) void convB_kernel(
    const float* __restrict__ W0, const float* __restrict__ U0,
    const float* __restrict__ W1, const float* __restrict__ U1,
    const float* __restrict__ W2, const float* __restrict__ U2,
    const float* __restrict__ W3, const float* __restrict__ U3,
    ush* __restrict__ Bf0, ush* __restrict__ Bf1,
    ush* __restrict__ Bf2, ush* __restrict__ Bf3)
{
    const int p = blockIdx.y;
    const float* W = p == 0 ? W0 : p == 1 ? W1 : p == 2 ? W2 : W3;
    const float* U = p == 0 ? U0 : p == 1 ? U1 : p == 2 ? U2 : U3;
    ush* Bf = p == 0 ? Bf0 : p == 1 ? Bf1 : p == 2 ? Bf2 : Bf3;
    const int i = blockIdx.x * 256 + threadIdx.x;
    const int n = i / 288, c4 = i % 288, col = c4 * 4;
    float4 v;
    if (col < Dm) {
        v = *(const float4*)(W + (size_t)n * Dm + col);
    } else {
        int ec = col - Dm, e = ec >> 4, r = ec & 15;
        v = *(const float4*)(U + ((size_t)(e * Dm + n)) * Rr + r);
    }
    store_h4(Bf + (size_t)n * KX + col, v);
}

// ------------------------------------------------------- V -> f16 (4 proj) --
__global__ __launch_bounds__(256) void convV_kernel(
    const float* __restrict__ V0, const float* __restrict__ V1,
    const float* __restrict__ V2, const float* __restrict__ V3,
    ush* __restrict__ Vf)
{
    const int p = blockIdx.y;
    const float* V = p == 0 ? V0 : p == 1 ? V1 : p == 2 ? V2 : V3;
    const size_t i = ((size_t)blockIdx.x * 256 + threadIdx.x) * 4;
    float4 v = *(const float4*)(V + i);
    store_h4(Vf + (size_t)p * Ee * Rr * Dm + i, v);
}

// --------------- ext as MFMA GEMM: xvs[s,j] = gS * (x[s,:] . Vsel[j,:]) -----
template<int NP>
__global__ __launch_bounds__(256) void ext_gemm(
    const ush* __restrict__ xf,
    const ush* __restrict__ Vf,                               // [4][128][1024]
    const float* __restrict__ S0, const float* __restrict__ S1,
    const float* __restrict__ S2,
    ush* __restrict__ o0, ush* __restrict__ o1, ush* __restrict__ o2,
    const float* __restrict__ gates, const int* __restrict__ idx, int pbase)
{
    __shared__ ush sA[64*32], sB[NP*32*32];
    const int mt = blockIdx.x, b = blockIdx.y;
    const int t = threadIdx.x, lane = t & 63, w = t >> 6;
    const int quad = lane >> 4, l16 = lane & 15;
    const int s0 = mt * 64;
    const int e0 = idx[b*2+0], e1 = idx[b*2+1];
    const float g0 = gates[b*2+0], g1 = gates[b*2+1];
    const int swsrc = ((lane & 3) ^ ((lane >> 3) & 3)) * 8;  // staging source chunk
    const int swrd  = ((quad ^ ((l16 >> 1) & 3)) * 8);       // read chunk

    {   // zero-fill output slots for this m-tile
        short8 z = {0,0,0,0,0,0,0,0};
        #pragma unroll
        for (int p = 0; p < NP; ++p) {
            ush* oo = p == 0 ? o0 : p == 1 ? o1 : o2;
            for (int i = t; i < 1024; i += 256) {
                const int row = i >> 4, c8 = i & 15;
                const int s = s0 + row;
                if (s < SQ) *(short8*)&oo[((size_t)(b * SQ + s)) * 128 + c8 * 8] = z;
            }
        }
    }

    floatx4 S[2*NP] = {};
    const int nloads = 4 + 2 * NP;

    for (int k0 = 0; k0 < Dm; k0 += 32) {
        __syncthreads();
        for (int ld = w; ld < nloads; ld += 4) {
            if (ld < 4) {
                int s = s0 + ld * 16 + (lane >> 2); if (s > SQ - 1) s = SQ - 1;
                load16(xf + ((size_t)(b * SQ + s)) * Dm + k0 + swsrc, &sA[ld * 512]);
            } else {
                const int g = ld - 4;                 // in [0, 2*NP)
                const int p = g >> 1, kk = g & 1;
                const int e = kk ? e1 : e0;
                const int r = lane >> 2;
                const ush* Vb = Vf + ((size_t)(pbase + p)) * Ee * Rr * Dm;
                load16(Vb + ((size_t)(e * Rr + r)) * Dm + k0 + swsrc, &sB[g * 512]);
            }
        }
        __syncthreads();
        const half8 a = *(const half8*)&sA[(w*16 + l16)*32 + swrd];
        #pragma unroll
        for (int ni = 0; ni < 2*NP; ++ni) {
            const half8 bb = *(const half8*)&sB[(ni*16 + l16)*32 + swrd];
            S[ni] = __builtin_amdgcn_mfma_f32_16x16x32_f16(a, bb, S[ni], 0, 0, 0);
        }
    }

    #pragma unroll
    for (int ni = 0; ni < 2*NP; ++ni) {
        const int p = ni >> 1, kk = ni & 1;
        const int e = kk ? e1 : e0;
        const float g = kk ? g1 : g0;
        const float* Sp = p == 0 ? S0 : p == 1 ? S1 : S2;
        const float scale = g * Sp[e * Rr + l16];
        ush* oo = p == 0 ? o0 : p == 1 ? o1 : o2;
        #pragma unroll
        for (int r = 0; r < 4; ++r) {
            const int s = s0 + w * 16 + quad * 4 + r;
            if (s < SQ)
                oo[((size_t)(b * SQ + s)) * 128 + e * 16 + l16] = f2h(S[ni][r] * scale);
        }
    }
}

// ------------------------------ f16 MFMA GEMM, K=1152 (1024+ext), BK=64 -----
// grid.x = 72*8 (n = x/72, m-stripe = x%72, dead if >=65) for XCD L2 reuse.
template<bool F32OUT>
__global__ __launch_bounds__(256) void gemm_mfma(
    const ush* __restrict__ A,
    const ush* __restrict__ E0, const ush* __restrict__ E1, const ush* __restrict__ E2,
    const ush* __restrict__ B0, const ush* __restrict__ B1, const ush* __restrict__ B2,
    const float* __restrict__ b0, const float* __restrict__ b1, const float* __restrict__ b2,
    void* __restrict__ y0, void* __restrict__ y1, void* __restrict__ y2,
    float scale0)
{
    const int stripe = blockIdx.x % 72;
    if (stripe >= 65) return;
    const int nb = blockIdx.x / 72;
    const int z = blockIdx.z;
    const ush* E = z == 0 ? E0 : z == 1 ? E1 : E2;
    const ush* Bm = z == 0 ? B0 : z == 1 ? B1 : B2;
    const float* bias = z == 0 ? b0 : z == 1 ? b1 : b2;
    void* y = z == 0 ? y0 : z == 1 ? y1 : y2;
    const float scale = z == 0 ? scale0 : 1.0f;

    __shared__ ush sA[128*64], sB[128*64];
    const int t = threadIdx.x, lane = t & 63, w = t >> 6;
    const int m0 = stripe * 128, n0 = nb * 128;
    const int row8 = lane >> 3, c8 = lane & 7;
    const int swk = (c8 ^ row8) * 8;            // swizzled source chunk offset
    const int wm = w >> 1, wn = w & 1;
    const int l16 = lane & 15, quad = lane >> 4;

    floatx4 acc[4][4] = {};

    for (int k0 = 0; k0 < KX; k0 += 64) {
        const ush* asrc; size_t astr; int acol;
        if (k0 < Dm) { asrc = A; astr = Dm;  acol = k0; }
        else         { asrc = E; astr = 128; acol = k0 - Dm; }
        __syncthreads();
        #pragma unroll
        for (int c = 0; c < 4; ++c) {
            const int j = c * 4 + w;            // 16 load units of 8 rows each
            const int rowl = j * 8 + row8;
            int rg = m0 + rowl; if (rg > NT - 1) rg = NT - 1;
            load16(asrc + (size_t)rg * astr + acol + swk, &sA[j * 512]);
            load16(Bm + (size_t)(n0 + rowl) * KX + k0 + swk, &sB[j * 512]);
        }
        __syncthreads();
        half8 af[4][2], bf[4][2];
        #pragma unroll
        for (int i = 0; i < 4; ++i) {
            const int ar = wm * 64 + i * 16 + l16;
            const int br = wn * 64 + i * 16 + l16;
            #pragma unroll
            for (int s = 0; s < 2; ++s) {
                af[i][s] = *(const half8*)&sA[ar * 64 + (((s*4 + quad) ^ (l16 & 7)) * 8)];
                bf[i][s] = *(const half8*)&sB[br * 64 + (((s*4 + quad) ^ (l16 & 7)) * 8)];
            }
        }
        #pragma unroll
        for (int s = 0; s < 2; ++s)
            #pragma unroll
            for (int mi = 0; mi < 4; ++mi)
                #pragma unroll
                for (int ni = 0; ni < 4; ++ni)
                    acc[mi][ni] = __builtin_amdgcn_mfma_f32_16x16x32_f16(af[mi][s], bf[ni][s], acc[mi][ni], 0, 0, 0);
    }

    #pragma unroll
    for (int mi = 0; mi < 4; ++mi) {
        #pragma unroll
        for (int ni = 0; ni < 4; ++ni) {
            const int col = n0 + wn*64 + ni*16 + l16;
            const float bsv = bias[col];
            const int rbase = m0 + wm*64 + mi*16 + quad * 4;
            #pragma unroll
            for (int r = 0; r < 4; ++r) {
                const int row = rbase + r;
                if (row < NT) {
                    const float val = (acc[mi][ni][r] + bsv) * scale;
                    if (F32OUT) ((float*)y)[(size_t)row * Dm + col] = val;
                    else        ((ush*)y)[(size_t)row * Dm + col] = f2h(val);
                }
            }
        }
    }
}

// ----------------------------------------- f16 MFMA flash attention ---------
// q,k,v are f16 (NT x Dm). writes ctx f16 into cf.
__global__ __launch_bounds__(256) void attn_mfma(
    const ush* __restrict__ q, const ush* __restrict__ k,
    const ush* __restrict__ v, ush* __restrict__ cf)
{
    __shared__ ush sK[64*LDP], sVt[64*LDP];
    __shared__ ush sP[4][16*LDP];
    const int qt = blockIdx.x, h = blockIdx.y, b = blockIdx.z;
    const int t = threadIdx.x, lane = t & 63, w = t >> 6;
    const int quad = lane >> 4, l16 = lane & 15;
    const size_t base = (size_t)b * SQ * Dm + (size_t)h * HD;

    // stage Q tile into sK, grab fragments
    #pragma unroll
    for (int i = 0; i < 2; ++i) {
        const int u = t + i * 256;
        const int row = u >> 3, c8 = u & 7;
        int s = qt * 64 + row; if (s > SQ - 1) s = SQ - 1;
        short8 ld = *(const short8*)(q + base + (size_t)s * Dm + c8 * 8);
        *(short8*)&sK[row*LDP + c8*8] = ld;
    }
    __syncthreads();
    half8 qf[2];
    #pragma unroll
    for (int s = 0; s < 2; ++s)
        qf[s] = *(const half8*)&sK[(w*16 + l16)*LDP + s*32 + quad*8];

    floatx4 O[4] = {};
    float mrow[4], lrow[4];
    #pragma unroll
    for (int r = 0; r < 4; ++r) { mrow[r] = -1e30f; lrow[r] = 0.f; }
    const bool active = (qt * 64 + w * 16) < SQ;

    for (int kt = 0; kt < 5; ++kt) {
        __syncthreads();
        #pragma unroll
        for (int i = 0; i < 2; ++i) {
            const int u = t + i * 256;
            const int row = u >> 3, c8 = u & 7;
            const int s = kt * 64 + row;
            short8 kv = {0,0,0,0,0,0,0,0}, vv = {0,0,0,0,0,0,0,0};
            if (s < SQ) {
                kv = *(const short8*)(k + base + (size_t)s * Dm + c8 * 8);
                vv = *(const short8*)(v + base + (size_t)s * Dm + c8 * 8);
            }
            *(short8*)&sK[row*LDP + c8*8] = kv;
            #pragma unroll
            for (int j = 0; j < 8; ++j)
                sVt[(c8*8 + j)*LDP + row] = ((ush*)&vv)[j];
        }
        __syncthreads();
        if (!active) continue;

        floatx4 S[4] = {};
        #pragma unroll
        for (int ni = 0; ni < 4; ++ni)
            #pragma unroll
            for (int s = 0; s < 2; ++s) {
                half8 kf = *(const half8*)&sK[(ni*16 + l16)*LDP + s*32 + quad*8];
                S[ni] = __builtin_amdgcn_mfma_f32_16x16x32_f16(qf[s], kf, S[ni], 0, 0, 0);
            }
        #pragma unroll
        for (int ni = 0; ni < 4; ++ni) {
            const int jg = kt * 64 + ni * 16 + l16;
            if (jg >= SQ) { S[ni][0] = -1e30f; S[ni][1] = -1e30f; S[ni][2] = -1e30f; S[ni][3] = -1e30f; }
        }
        float mnew[4], alpha[4];
        #pragma unroll
        for (int r = 0; r < 4; ++r) {
            float mx = fmaxf(fmaxf(S[0][r], S[1][r]), fmaxf(S[2][r], S[3][r]));
            #pragma unroll
            for (int off = 1; off < 16; off <<= 1) mx = fmaxf(mx, __shfl_xor(mx, off, 64));
            mnew[r] = fmaxf(mrow[r], mx);
            alpha[r] = __expf(mrow[r] - mnew[r]);
            mrow[r] = mnew[r];
        }
        float p[4][4], rs[4];
        #pragma unroll
        for (int r = 0; r < 4; ++r) rs[r] = 0.f;
        #pragma unroll
        for (int ni = 0; ni < 4; ++ni)
            #pragma unroll
            for (int r = 0; r < 4; ++r) {
                float e = __expf(S[ni][r] - mnew[r]);
                p[ni][r] = e; rs[r] += e;
            }
        #pragma unroll
        for (int r = 0; r < 4; ++r) {
            #pragma unroll
            for (int off = 1; off < 16; off <<= 1) rs[r] += __shfl_xor(rs[r], off, 64);
            lrow[r] = lrow[r] * alpha[r] + rs[r];
        }
        #pragma unroll
        for (int ni = 0; ni < 4; ++ni)
            #pragma unroll
            for (int r = 0; r < 4; ++r) O[ni][r] *= alpha[r];
        #pragma unroll
        for (int ni = 0; ni < 4; ++ni)
            #pragma unroll
            for (int r = 0; r < 4; ++r)
                sP[w][(quad*4 + r)*LDP + ni*16 + l16] = f2h(p[ni][r]);
        #pragma unroll
        for (int ni = 0; ni < 4; ++ni)
            #pragma unroll
            for (int s = 0; s < 2; ++s) {
                half8 a  = *(const half8*)&sP[w][l16*LDP + s*32 + quad*8];
                half8 bb = *(const half8*)&sVt[(ni*16 + l16)*LDP + s*32 + quad*8];
                O[ni] = __builtin_amdgcn_mfma_f32_16x16x32_f16(a, bb, O[ni], 0, 0, 0);
            }
    }

    if (active) {
        #pragma unroll
        for (int ni = 0; ni < 4; ++ni) {
            const int col = h * HD + ni * 16 + l16;
            #pragma unroll
            for (int r = 0; r < 4; ++r) {
                const int s = qt * 64 + w * 16 + quad * 4 + r;
                if (s < SQ)
                    cf[((size_t)(b * SQ + s)) * Dm + col] = f2h(O[ni][r] / lrow[r]);
            }
        }
    }
}

// ------------------------------------------------------------------ launch --
extern "C" void kernel_launch(void* const* d_in, const int* in_sizes, int n_in,
                              void* d_out, int out_size, void* d_ws, size_t ws_size,
                              hipStream_t stream)
{
    const float* x   = (const float*)d_in[0];
    const float* gw1 = (const float*)d_in[1];
    const float* gb1 = (const float*)d_in[2];
    const float* gw2 = (const float*)d_in[3];
    const float* gb2 = (const float*)d_in[4];
    const float *Wm[4], *U[4], *Sv[4], *Vv[4], *bias[4];
    for (int p = 0; p < 4; ++p) {
        Wm[p]   = (const float*)d_in[5 + p*5 + 0];
        U[p]    = (const float*)d_in[5 + p*5 + 1];
        Sv[p]   = (const float*)d_in[5 + p*5 + 2];
        Vv[p]   = (const float*)d_in[5 + p*5 + 3];
        bias[p] = (const float*)d_in[5 + p*5 + 4];
    }
    char* wsb   = (char*)d_ws;
    float* gates = (float*)wsb;           // 64 floats
    int*   idx   = (int*)(wsb + 256);     // 64 ints
    float* pool  = (float*)(wsb + 1024);  // 32*16*1024 floats = 2 MB
    ush* p = (ush*)(wsb + 1024 + (size_t)Bb * 16 * Dm * 4);
    ush* xf = p; p += (size_t)NT * Dm;
    ush* ef[4];
    for (int i = 0; i < 4; ++i) { ef[i] = p; p += (size_t)NT * 128; }
    ush* Bf[4];
    for (int i = 0; i < 4; ++i) { Bf[i] = p; p += (size_t)1024 * KX; }
    ush* Vf = p; p += (size_t)4 * Ee * Rr * Dm;
    ush* qf = p; p += (size_t)NT * Dm;
    ush* kf = p; p += (size_t)NT * Dm;
    ush* vf = p; p += (size_t)NT * Dm;

    pool_kernel<<<dim3(16, Bb), 256, 0, stream>>>(x, pool);
    gating2_kernel<<<Bb, 256, 0, stream>>>(pool, gw1, gb1, gw2, gb2, gates, idx);
    convx_kernel<<<NT, 256, 0, stream>>>(x, xf);
    convV_kernel<<<dim3(128, 4), 256, 0, stream>>>(Vv[0], Vv[1], Vv[2], Vv[3], Vf);
    convB_kernel<<<dim3(1152, 4), 256, 0, stream>>>(
        Wm[0], U[0], Wm[1], U[1], Wm[2], U[2], Wm[3], U[3],
        Bf[0], Bf[1], Bf[2], Bf[3]);

    ext_gemm<3><<<dim3(5, Bb), 256, 0, stream>>>(xf, Vf,
        Sv[0], Sv[1], Sv[2], ef[0], ef[1], ef[2], gates, idx, 0);

    gemm_mfma<false><<<dim3(576, 1, 3), 256, 0, stream>>>(
        xf, ef[0], ef[1], ef[2], Bf[0], Bf[1], Bf[2],
        bias[0], bias[1], bias[2], qf, kf, vf, 0.125f);

    // attention writes ctx f16 into xf (x no longer needed)
    attn_mfma<<<dim3(5, 16, Bb), 256, 0, stream>>>(qf, kf, vf, xf);

    ext_gemm<1><<<dim3(5, Bb), 256, 0, stream>>>(xf, Vf,
        Sv[3], Sv[3], Sv[3], ef[3], ef[3], ef[3], gates, idx, 3);

    gemm_mfma<true><<<dim3(576, 1, 1), 256, 0, stream>>>(
        xf, ef[3], ef[3], ef[3], Bf[3], Bf[3], Bf[3],
        bias[3], bias[3], bias[3], d_out, d_out, d_out, 1.0f);
}

// Round 7
// 436.665 us; speedup vs baseline: 7.4002x; 1.0805x over previous
//
#include <hip/hip_runtime.h>
#include <math.h>

#define Bb   32
#define SQ   257
#define SQV  320       // padded vt row stride (covers kt*64..+63 reads)
#define Dm   1024
#define HD   64
#define Ee   8
#define Rr   16
#define GHh  256
#define NT   (Bb*SQ)   // 8224
#define KX   1152      // 1024 + E*R extension
#define LDP  72        // padded LDS row (64 ush + 8) — attn only

typedef unsigned short ush;
typedef _Float16 h16;
typedef __attribute__((ext_vector_type(8))) _Float16 half8;
typedef __attribute__((ext_vector_type(4))) _Float16 half4;
typedef __attribute__((ext_vector_type(8))) short short8;
typedef __attribute__((ext_vector_type(4))) float floatx4;
typedef __attribute__((ext_vector_type(16))) float floatx16;

__device__ __forceinline__ ush f2h(float f) {
    union { h16 h; ush u; } a; a.h = (h16)f; return a.u;
}
__device__ __forceinline__ void store_h4(ush* p, float4 v) {
    half4 h; h.x = (h16)v.x; h.y = (h16)v.y; h.z = (h16)v.z; h.w = (h16)v.w;
    *(half4*)p = h;
}
__device__ __forceinline__ void load16(const ush* g, ush* l) {
    __builtin_amdgcn_global_load_lds(
        (const __attribute__((address_space(1))) unsigned int*)g,
        (__attribute__((address_space(3))) unsigned int*)l,
        16, 0, 0);
}

// ------------------------------------------------------------ zero-fill -----
__global__ __launch_bounds__(256) void zero_kernel(ush* __restrict__ p)
{
    const size_t i = ((size_t)blockIdx.x * 256 + threadIdx.x) * 8;
    short8 z = {0,0,0,0,0,0,0,0};
    *(short8*)(p + i) = z;
}

// ----------------------------------------------------- gating stage A: pool -
__global__ __launch_bounds__(256) void pool_kernel(
    const float* __restrict__ x, float* __restrict__ pp)
{
    const int c = blockIdx.x, b = blockIdx.y, t = threadIdx.x;
    const int s0 = c * 16, s1 = (c == 15) ? SQ : s0 + 16;
    float4 acc = make_float4(0.f, 0.f, 0.f, 0.f);
    const float* xp = x + ((size_t)b * SQ + s0) * Dm + t * 4;
    for (int s = s0; s < s1; ++s, xp += Dm) {
        float4 v = *(const float4*)xp;
        acc.x += v.x; acc.y += v.y; acc.z += v.z; acc.w += v.w;
    }
    *(float4*)(pp + ((size_t)b * 16 + c) * Dm + t * 4) = acc;
}

// ----------------------------------------------- gating stage B: MLP + top2 -
__global__ __launch_bounds__(256) void gating2_kernel(
    const float* __restrict__ pp, const float* __restrict__ gw1,
    const float* __restrict__ gb1, const float* __restrict__ gw2,
    const float* __restrict__ gb2,
    float* __restrict__ gates, int* __restrict__ idx)
{
    __shared__ float pooled[Dm];
    __shared__ float hbuf[GHh];
    __shared__ float logits[Ee];
    const int b = blockIdx.x, t = threadIdx.x;
    const int w = t >> 6, lane = t & 63;

    float4 acc = make_float4(0.f, 0.f, 0.f, 0.f);
    for (int c = 0; c < 16; ++c) {
        float4 v = *(const float4*)(pp + ((size_t)b * 16 + c) * Dm + t * 4);
        acc.x += v.x; acc.y += v.y; acc.z += v.z; acc.w += v.w;
    }
    const float sc = 1.0f / SQ;
    pooled[t*4+0] = acc.x * sc; pooled[t*4+1] = acc.y * sc;
    pooled[t*4+2] = acc.z * sc; pooled[t*4+3] = acc.w * sc;
    __syncthreads();

    for (int oi = 0; oi < 64; ++oi) {
        const int o = w * 64 + oi;
        const float* g = gw1 + (size_t)o * Dm;
        float s = 0.f;
        #pragma unroll
        for (int i = 0; i < 16; ++i) s += pooled[lane + i*64] * g[lane + i*64];
        for (int off = 32; off > 0; off >>= 1) s += __shfl_down(s, off, 64);
        if (lane == 0) hbuf[o] = fmaxf(s + gb1[o], 0.f);
    }
    __syncthreads();
    if (t < Ee) {
        const float* g = gw2 + t * GHh;
        float s = 0.f;
        for (int j = 0; j < GHh; ++j) s += hbuf[j] * g[j];
        logits[t] = s + gb2[t];
    }
    __syncthreads();
    if (t == 0) {
        int i1 = 0; float v1 = logits[0];
        for (int e = 1; e < Ee; ++e) if (logits[e] > v1) { v1 = logits[e]; i1 = e; }
        int i2 = 0; float v2 = -1e30f;
        for (int e = 0; e < Ee; ++e) if (e != i1 && logits[e] > v2) { v2 = logits[e]; i2 = e; }
        float e2 = __expf(v2 - v1);
        float inv = 1.f / (1.f + e2);
        gates[b*2+0] = inv; gates[b*2+1] = e2 * inv;
        idx[b*2+0] = i1; idx[b*2+1] = i2;
    }
}

// ------------------------------------------------------- fp32 -> f16 (rows) -
__global__ __launch_bounds__(256) void convx_kernel(
    const float* __restrict__ x, ush* __restrict__ xf)
{
    const int m = blockIdx.x, t = threadIdx.x;
    float4 v = *(const float4*)(x + (size_t)m * Dm + t * 4);
    store_h4(xf + (size_t)m * Dm + t * 4, v);
}

// ------------------- W,U -> f16 B matrix (1024x1152) and V -> f16, merged ---
__global__ __launch_bounds__(256) void convBV_kernel(
    const float* __restrict__ W0, const float* __restrict__ U0,
    const float* __restrict__ W1, const float* __restrict__ U1,
    const float* __restrict__ W2, const float* __restrict__ U2,
    const float* __restrict__ W3, const float* __restrict__ U3,
    const float* __restrict__ V0, const float* __restrict__ V1,
    const float* __restrict__ V2, const float* __restrict__ V3,
    ush* __restrict__ Bf0, ush* __restrict__ Bf1,
    ush* __restrict__ Bf2, ush* __restrict__ Bf3,
    ush* __restrict__ Vf)
{
    const int p = blockIdx.y;
    if (blockIdx.x < 1152) {
        const float* W = p == 0 ? W0 : p == 1 ? W1 : p == 2 ? W2 : W3;
        const float* U = p == 0 ? U0 : p == 1 ? U1 : p == 2 ? U2 : U3;
        ush* Bf = p == 0 ? Bf0 : p == 1 ? Bf1 : p == 2 ? Bf2 : Bf3;
        const int i = blockIdx.x * 256 + threadIdx.x;
        const int n = i / 288, c4 = i % 288, col = c4 * 4;
        float4 v;
        if (col < Dm) {
            v = *(const float4*)(W + (size_t)n * Dm + col);
        } else {
            int ec = col - Dm, e = ec >> 4, r = ec & 15;
            v = *(const float4*)(U + ((size_t)(e * Dm + n)) * Rr + r);
        }
        store_h4(Bf + (size_t)n * KX + col, v);
    } else {
        const float* V = p == 0 ? V0 : p == 1 ? V1 : p == 2 ? V2 : V3;
        const size_t i = ((size_t)(blockIdx.x - 1152) * 256 + threadIdx.x) * 4;
        float4 v = *(const float4*)(V + i);
        store_h4(Vf + (size_t)p * Ee * Rr * Dm + i, v);
    }
}

// --------------- ext as MFMA GEMM: xvs[s,j] = gS * (x[s,:] . Vsel[j,:]) -----
// grid (5 m-tiles, Bb, 2 experts). outputs pre-zeroed by zero_kernel.
template<int NP>
__global__ __launch_bounds__(256) void ext_gemm(
    const ush* __restrict__ xf,
    const ush* __restrict__ Vf,                               // [4][128][1024]
    const float* __restrict__ S0, const float* __restrict__ S1,
    const float* __restrict__ S2,
    ush* __restrict__ o0, ush* __restrict__ o1, ush* __restrict__ o2,
    const float* __restrict__ gates, const int* __restrict__ idx, int pbase)
{
    __shared__ ush sA[64*32], sB[NP*16*32];
    const int mt = blockIdx.x, b = blockIdx.y, kk = blockIdx.z;
    const int t = threadIdx.x, lane = t & 63, w = t >> 6;
    const int quad = lane >> 4, l16 = lane & 15;
    const int s0 = mt * 64;
    const int e = idx[b*2+kk];
    const float g = gates[b*2+kk];

    const int rl = lane >> 2;
    const int swsrc = ((lane & 3) ^ ((lane >> 3) & 3)) * 8;  // staging chunk
    const int swrd  = ((quad ^ ((l16 >> 1) & 3)) * 8);       // read chunk

    // hoisted staging pointers: wave w stages A rows s0+w*16..+15; waves<NP stage B
    int sa = s0 + w * 16 + rl; if (sa > SQ - 1) sa = SQ - 1;
    const ush* aptr = xf + ((size_t)(b * SQ + sa)) * Dm + swsrc;
    const ush* bptr = (w < NP)
        ? Vf + ((size_t)(pbase + w)) * Ee * Rr * Dm + ((size_t)(e * Rr + rl)) * Dm + swsrc
        : nullptr;
    ush* la = &sA[w * 512];
    ush* lb = (w < NP) ? &sB[w * 512] : nullptr;

    floatx4 S[NP] = {};

    for (int it = 0; it < 32; ++it) {
        __syncthreads();
        load16(aptr, la); aptr += 32;
        if (w < NP) { load16(bptr, lb); bptr += 32; }
        __syncthreads();
        const half8 a = *(const half8*)&sA[(w*16 + l16)*32 + swrd];
        #pragma unroll
        for (int p = 0; p < NP; ++p) {
            const half8 bb = *(const half8*)&sB[(p*16 + l16)*32 + swrd];
            S[p] = __builtin_amdgcn_mfma_f32_16x16x32_f16(a, bb, S[p], 0, 0, 0);
        }
    }

    #pragma unroll
    for (int p = 0; p < NP; ++p) {
        const float* Sp = p == 0 ? S0 : p == 1 ? S1 : S2;
        const float scale = g * Sp[e * Rr + l16];
        ush* oo = p == 0 ? o0 : p == 1 ? o1 : o2;
        #pragma unroll
        for (int r = 0; r < 4; ++r) {
            const int s = s0 + w * 16 + quad * 4 + r;
            if (s < SQ)
                oo[((size_t)(b * SQ + s)) * 128 + e * 16 + l16] = f2h(S[p][r] * scale);
        }
    }
}

// ------------- f16 MFMA GEMM (32x32x16), K=1152 (1024+ext), BK=64 -----------
// grid.x = 72*8 (n = x/72, m-stripe = x%72, dead if >=65) for XCD L2 reuse.
// MODE 0: QKV — z0->qf f16 (*0.125), z1->kf f16, z2->vt transposed f16.
// MODE 1: O   — single z, f32 out.
template<int MODE>
__global__ __launch_bounds__(256) void gemm_mfma(
    const ush* __restrict__ A,
    const ush* __restrict__ E0, const ush* __restrict__ E1, const ush* __restrict__ E2,
    const ush* __restrict__ B0, const ush* __restrict__ B1, const ush* __restrict__ B2,
    const float* __restrict__ b0, const float* __restrict__ b1, const float* __restrict__ b2,
    ush* __restrict__ y0, ush* __restrict__ y1, ush* __restrict__ vt,
    float* __restrict__ yo, float qscale)
{
    const int stripe = blockIdx.x % 72;
    if (stripe >= 65) return;
    const int nb = blockIdx.x / 72;
    const int z = blockIdx.z;
    const ush* E = z == 0 ? E0 : z == 1 ? E1 : E2;
    const ush* Bm = z == 0 ? B0 : z == 1 ? B1 : B2;
    const float* bias = z == 0 ? b0 : z == 1 ? b1 : b2;

    __shared__ ush sA[128*64], sB[128*64];
    const int t = threadIdx.x, lane = t & 63, w = t >> 6;
    const int m0 = stripe * 128, n0 = nb * 128;
    const int row8 = lane >> 3, c8l = lane & 7;
    const int swk = (c8l ^ row8) * 8;
    const int wm = w >> 1, wn = w & 1;
    const int l31 = lane & 31, h5 = lane >> 5;

    // hoisted staging pointers (4 load units per wave for A and B each)
    const ush* ap[4]; const ush* ep[4]; const ush* bp[4];
    ush *la[4], *lb[4];
    #pragma unroll
    for (int c = 0; c < 4; ++c) {
        const int j = c * 4 + w;
        const int rowl = j * 8 + row8;
        int rga = m0 + rowl; if (rga > NT - 1) rga = NT - 1;
        ap[c] = A + (size_t)rga * Dm + swk;
        ep[c] = E + (size_t)rga * 128 + swk;
        bp[c] = Bm + (size_t)(n0 + rowl) * KX + swk;
        la[c] = &sA[j * 512];
        lb[c] = &sB[j * 512];
    }

    // hoisted LDS read offsets
    int aofs[4][2], bofs[4][2];
    #pragma unroll
    for (int s = 0; s < 4; ++s)
        #pragma unroll
        for (int i = 0; i < 2; ++i) {
            const int g = s * 2 + h5;
            aofs[s][i] = (wm*64 + i*32 + l31) * 64 + ((g ^ (l31 & 7)) * 8);
            bofs[s][i] = (wn*64 + i*32 + l31) * 64 + ((g ^ (l31 & 7)) * 8);
        }

    floatx16 acc[2][2] = {};

    for (int it = 0; it < 16; ++it) {       // main K: xf columns 0..1023
        __syncthreads();
        #pragma unroll
        for (int c = 0; c < 4; ++c) {
            load16(ap[c], la[c]); ap[c] += 64;
            load16(bp[c], lb[c]); bp[c] += 64;
        }
        __syncthreads();
        #pragma unroll
        for (int s = 0; s < 4; ++s) {
            half8 af0 = *(const half8*)&sA[aofs[s][0]];
            half8 af1 = *(const half8*)&sA[aofs[s][1]];
            half8 bf0 = *(const half8*)&sB[bofs[s][0]];
            half8 bf1 = *(const half8*)&sB[bofs[s][1]];
            acc[0][0] = __builtin_amdgcn_mfma_f32_32x32x16_f16(af0, bf0, acc[0][0], 0, 0, 0);
            acc[0][1] = __builtin_amdgcn_mfma_f32_32x32x16_f16(af0, bf1, acc[0][1], 0, 0, 0);
            acc[1][0] = __builtin_amdgcn_mfma_f32_32x32x16_f16(af1, bf0, acc[1][0], 0, 0, 0);
            acc[1][1] = __builtin_amdgcn_mfma_f32_32x32x16_f16(af1, bf1, acc[1][1], 0, 0, 0);
        }
    }
    for (int it = 0; it < 2; ++it) {        // ext K: E columns 0..127
        __syncthreads();
        #pragma unroll
        for (int c = 0; c < 4; ++c) {
            load16(ep[c], la[c]); ep[c] += 64;
            load16(bp[c], lb[c]); bp[c] += 64;
        }
        __syncthreads();
        #pragma unroll
        for (int s = 0; s < 4; ++s) {
            half8 af0 = *(const half8*)&sA[aofs[s][0]];
            half8 af1 = *(const half8*)&sA[aofs[s][1]];
            half8 bf0 = *(const half8*)&sB[bofs[s][0]];
            half8 bf1 = *(const half8*)&sB[bofs[s][1]];
            acc[0][0] = __builtin_amdgcn_mfma_f32_32x32x16_f16(af0, bf0, acc[0][0], 0, 0, 0);
            acc[0][1] = __builtin_amdgcn_mfma_f32_32x32x16_f16(af0, bf1, acc[0][1], 0, 0, 0);
            acc[1][0] = __builtin_amdgcn_mfma_f32_32x32x16_f16(af1, bf0, acc[1][0], 0, 0, 0);
            acc[1][1] = __builtin_amdgcn_mfma_f32_32x32x16_f16(af1, bf1, acc[1][1], 0, 0, 0);
        }
    }

    // epilogue — 32x32 C layout: col=lane&31, row=(r&3)+8*(r>>2)+4*(lane>>5)
    #pragma unroll
    for (int mi = 0; mi < 2; ++mi) {
        #pragma unroll
        for (int ni = 0; ni < 2; ++ni) {
            const int col = n0 + wn*64 + ni*32 + l31;
            const float bsv = bias[col];
            const int rb = m0 + wm*64 + mi*32 + 4*h5;
            #pragma unroll
            for (int r = 0; r < 16; ++r) {
                const int row = rb + (r & 3) + 8 * (r >> 2);
                if (row < NT) {
                    const float val = acc[mi][ni][r] + bsv;
                    if (MODE == 1) {
                        yo[(size_t)row * Dm + col] = val;
                    } else if (z == 2) {
                        const int b_ = row / SQ, s_ = row - b_ * SQ;
                        const int h_ = col >> 6, d_ = col & 63;
                        vt[(((size_t)(b_ * 16 + h_)) * 64 + d_) * SQV + s_] = f2h(val);
                    } else if (z == 1) {
                        y1[(size_t)row * Dm + col] = f2h(val);
                    } else {
                        y0[(size_t)row * Dm + col] = f2h(val * qscale);
                    }
                }
            }
        }
    }
}

// ----------------------------------------- f16 MFMA flash attention ---------
// q,k f16 row-major (NT x Dm); vt f16 transposed [(b*16+h)*64+d][SQV].
__global__ __launch_bounds__(256) void attn_mfma(
    const ush* __restrict__ q, const ush* __restrict__ k,
    const ush* __restrict__ vt, ush* __restrict__ cf)
{
    __shared__ ush sK[64*LDP], sVt[64*LDP];
    __shared__ ush sP[4][16*LDP];
    const int qt = blockIdx.x, h = blockIdx.y, b = blockIdx.z;
    const int t = threadIdx.x, lane = t & 63, w = t >> 6;
    const int quad = lane >> 4, l16 = lane & 15;
    const size_t base = (size_t)b * SQ * Dm + (size_t)h * HD;
    const size_t vbase = ((size_t)(b * 16 + h)) * 64 * SQV;

    #pragma unroll
    for (int i = 0; i < 2; ++i) {
        const int u = t + i * 256;
        const int row = u >> 3, c8 = u & 7;
        int s = qt * 64 + row; if (s > SQ - 1) s = SQ - 1;
        short8 ld = *(const short8*)(q + base + (size_t)s * Dm + c8 * 8);
        *(short8*)&sK[row*LDP + c8*8] = ld;
    }
    __syncthreads();
    half8 qf[2];
    #pragma unroll
    for (int s = 0; s < 2; ++s)
        qf[s] = *(const half8*)&sK[(w*16 + l16)*LDP + s*32 + quad*8];

    floatx4 O[4] = {};
    float mrow[4], lrow[4];
    #pragma unroll
    for (int r = 0; r < 4; ++r) { mrow[r] = -1e30f; lrow[r] = 0.f; }
    const bool active = (qt * 64 + w * 16) < SQ;

    for (int kt = 0; kt < 5; ++kt) {
        __syncthreads();
        #pragma unroll
        for (int i = 0; i < 2; ++i) {
            const int u = t + i * 256;
            const int row = u >> 3, c8 = u & 7;
            const int s = kt * 64 + row;
            short8 kv = {0,0,0,0,0,0,0,0};
            if (s < SQ) kv = *(const short8*)(k + base + (size_t)s * Dm + c8 * 8);
            *(short8*)&sK[row*LDP + c8*8] = kv;
            // V^T tile: row = d (u>>3), cols = keys kt*64 + c8*8..+7 (vector load)
            short8 vv = *(const short8*)(vt + vbase + (size_t)row * SQV + kt*64 + c8*8);
            *(short8*)&sVt[row*LDP + c8*8] = vv;
        }
        __syncthreads();
        if (!active) continue;

        floatx4 S[4] = {};
        #pragma unroll
        for (int ni = 0; ni < 4; ++ni)
            #pragma unroll
            for (int s = 0; s < 2; ++s) {
                half8 kf = *(const half8*)&sK[(ni*16 + l16)*LDP + s*32 + quad*8];
                S[ni] = __builtin_amdgcn_mfma_f32_16x16x32_f16(qf[s], kf, S[ni], 0, 0, 0);
            }
        #pragma unroll
        for (int ni = 0; ni < 4; ++ni) {
            const int jg = kt * 64 + ni * 16 + l16;
            if (jg >= SQ) { S[ni][0] = -1e30f; S[ni][1] = -1e30f; S[ni][2] = -1e30f; S[ni][3] = -1e30f; }
        }
        float mnew[4], alpha[4];
        #pragma unroll
        for (int r = 0; r < 4; ++r) {
            float mx = fmaxf(fmaxf(S[0][r], S[1][r]), fmaxf(S[2][r], S[3][r]));
            #pragma unroll
            for (int off = 1; off < 16; off <<= 1) mx = fmaxf(mx, __shfl_xor(mx, off, 64));
            mnew[r] = fmaxf(mrow[r], mx);
            alpha[r] = __expf(mrow[r] - mnew[r]);
            mrow[r] = mnew[r];
        }
        float p[4][4], rs[4];
        #pragma unroll
        for (int r = 0; r < 4; ++r) rs[r] = 0.f;
        #pragma unroll
        for (int ni = 0; ni < 4; ++ni)
            #pragma unroll
            for (int r = 0; r < 4; ++r) {
                float e = __expf(S[ni][r] - mnew[r]);
                p[ni][r] = e; rs[r] += e;
            }
        #pragma unroll
        for (int r = 0; r < 4; ++r) {
            #pragma unroll
            for (int off = 1; off < 16; off <<= 1) rs[r] += __shfl_xor(rs[r], off, 64);
            lrow[r] = lrow[r] * alpha[r] + rs[r];
        }
        #pragma unroll
        for (int ni = 0; ni < 4; ++ni)
            #pragma unroll
            for (int r = 0; r < 4; ++r) O[ni][r] *= alpha[r];
        #pragma unroll
        for (int ni = 0; ni < 4; ++ni)
            #pragma unroll
            for (int r = 0; r < 4; ++r)
                sP[w][(quad*4 + r)*LDP + ni*16 + l16] = f2h(p[ni][r]);
        #pragma unroll
        for (int ni = 0; ni < 4; ++ni)
            #pragma unroll
            for (int s = 0; s < 2; ++s) {
                half8 a  = *(const half8*)&sP[w][l16*LDP + s*32 + quad*8];
                half8 bb = *(const half8*)&sVt[(ni*16 + l16)*LDP + s*32 + quad*8];
                O[ni] = __builtin_amdgcn_mfma_f32_16x16x32_f16(a, bb, O[ni], 0, 0, 0);
            }
    }

    if (active) {
        #pragma unroll
        for (int ni = 0; ni < 4; ++ni) {
            const int col = h * HD + ni * 16 + l16;
            #pragma unroll
            for (int r = 0; r < 4; ++r) {
                const int s = qt * 64 + w * 16 + quad * 4 + r;
                if (s < SQ)
                    cf[((size_t)(b * SQ + s)) * Dm + col] = f2h(O[ni][r] / lrow[r]);
            }
        }
    }
}

// ------------------------------------------------------------------ launch --
extern "C" void kernel_launch(void* const* d_in, const int* in_sizes, int n_in,
                              void* d_out, int out_size, void* d_ws, size_t ws_size,
                              hipStream_t stream)
{
    const float* x   = (const float*)d_in[0];
    const float* gw1 = (const float*)d_in[1];
    const float* gb1 = (const float*)d_in[2];
    const float* gw2 = (const float*)d_in[3];
    const float* gb2 = (const float*)d_in[4];
    const float *Wm[4], *U[4], *Sv[4], *Vv[4], *bias[4];
    for (int p = 0; p < 4; ++p) {
        Wm[p]   = (const float*)d_in[5 + p*5 + 0];
        U[p]    = (const float*)d_in[5 + p*5 + 1];
        Sv[p]   = (const float*)d_in[5 + p*5 + 2];
        Vv[p]   = (const float*)d_in[5 + p*5 + 3];
        bias[p] = (const float*)d_in[5 + p*5 + 4];
    }
    char* wsb   = (char*)d_ws;
    float* gates = (float*)wsb;           // 64 floats
    int*   idx   = (int*)(wsb + 256);     // 64 ints
    float* pool  = (float*)(wsb + 1024);  // 32*16*1024 floats = 2 MB
    ush* p = (ush*)(wsb + 1024 + (size_t)Bb * 16 * Dm * 4);
    ush* xf = p; p += (size_t)NT * Dm;
    ush* ef[4];
    for (int i = 0; i < 4; ++i) { ef[i] = p; p += (size_t)NT * 128; }
    ush* Bf[4];
    for (int i = 0; i < 4; ++i) { Bf[i] = p; p += (size_t)1024 * KX; }
    ush* Vf = p; p += (size_t)4 * Ee * Rr * Dm;
    ush* qf = p; p += (size_t)NT * Dm;
    ush* kf = p; p += (size_t)NT * Dm;
    ush* vt = p; p += (size_t)Bb * 16 * 64 * SQV;

    zero_kernel<<<2056, 256, 0, stream>>>(ef[0]);   // ef[0..3] contiguous
    pool_kernel<<<dim3(16, Bb), 256, 0, stream>>>(x, pool);
    gating2_kernel<<<Bb, 256, 0, stream>>>(pool, gw1, gb1, gw2, gb2, gates, idx);
    convx_kernel<<<NT, 256, 0, stream>>>(x, xf);
    convBV_kernel<<<dim3(1280, 4), 256, 0, stream>>>(
        Wm[0], U[0], Wm[1], U[1], Wm[2], U[2], Wm[3], U[3],
        Vv[0], Vv[1], Vv[2], Vv[3],
        Bf[0], Bf[1], Bf[2], Bf[3], Vf);

    ext_gemm<3><<<dim3(5, Bb, 2), 256, 0, stream>>>(xf, Vf,
        Sv[0], Sv[1], Sv[2], ef[0], ef[1], ef[2], gates, idx, 0);

    gemm_mfma<0><<<dim3(576, 1, 3), 256, 0, stream>>>(
        xf, ef[0], ef[1], ef[2], Bf[0], Bf[1], Bf[2],
        bias[0], bias[1], bias[2], qf, kf, vt, nullptr, 0.125f);

    // attention writes ctx f16 into xf (x no longer needed)
    attn_mfma<<<dim3(5, 16, Bb), 256, 0, stream>>>(qf, kf, vt, xf);

    ext_gemm<1><<<dim3(5, Bb, 2), 256, 0, stream>>>(xf, Vf,
        Sv[3], Sv[3], Sv[3], ef[3], ef[3], ef[3], gates, idx, 3);

    gemm_mfma<1><<<dim3(576, 1, 1), 256, 0, stream>>>(
        xf, ef[3], ef[3], ef[3], Bf[3], Bf[3], Bf[3],
        bias[3], bias[3], bias[3], nullptr, nullptr, nullptr, (float*)d_out, 1.0f);
}